// Round 1
// baseline (84554.620 us; speedup 1.0000x reference)
//
#include <hip/hip_runtime.h>

#define NWG 256
#define NT  512
#define ROWS 8
#define JPT 8
#define NDIM 4096
#define N_ADMM 30
#define N_CG 15

static_assert(NWG * ROWS == 2048, "row partition");
static_assert(NT * JPT == NDIM, "col partition");

__device__ __forceinline__ float wred64(float v) {
#pragma unroll
  for (int m = 32; m > 0; m >>= 1) v += __shfl_xor(v, m, 64);
  return v;
}

__global__ __launch_bounds__(NT)
void admm_lp_kernel(const float* __restrict__ A, const float* __restrict__ cvec,
                    const float* __restrict__ lbv, const float* __restrict__ ubv,
                    const float* __restrict__ dvec, const float* __restrict__ evec,
                    const float* __restrict__ gcp, const float* __restrict__ gbp,
                    const float* __restrict__ rhop, const float* __restrict__ sigp,
                    const float* __restrict__ alp,
                    float* __restrict__ out, unsigned char* __restrict__ ws)
{
  const int tid = threadIdx.x;
  const int w = blockIdx.x;
  const int j0 = tid * JPT;        // this thread's column base (global)
  const int row0 = w * ROWS;       // this WG's first row

  unsigned* flags = (unsigned*)(ws);                       // 16 KB, memset to 0
  float* pkp  = (float*)(ws + (1u << 14));                 // 256 * 64B padded
  float* rzp  = (float*)(ws + (2u << 14));
  float* z_g  = (float*)(ws + (3u << 14));                 // 4096 f32
  float* xt_g = (float*)(ws + (4u << 14));                 // 4096 f32
  float* P    = (float*)(ws + (5u << 14));                 // [256][4096] f32
  float* R    = (float*)(ws + (5u << 14) + (size_t)NWG * NDIM * 4);

  __shared__ float s_scal[6];
  __shared__ float s_r8[8];
  __shared__ float s_b[1];
  __shared__ float s_rz[1];
  __shared__ float dred[8][ROWS];
  __shared__ float tvec[ROWS];
  __shared__ float zb[ROWS], yb[ROWS], lbs[ROWS], ubs[ROWS], uvec[ROWS];
  __shared__ float xa[16], cs[16], Md[16], r_l[16], pchunk[16];
  __shared__ float sredA[32][16], sredB[32][16];
  __shared__ int s_dead;

  float areg[ROWS][JPT];   // this thread's slice of A (registers)
  float preg[JPT];         // this thread's slice of CG's p

  unsigned gen = 0;

  auto gridbar = [&]() {
    ++gen;
    __threadfence();
    __syncthreads();
    if (tid == 0)
      __hip_atomic_store(&flags[w * 16], gen, __ATOMIC_RELEASE, __HIP_MEMORY_SCOPE_AGENT);
    if (tid < NWG && !s_dead) {
      int spin = 0;
      while (__hip_atomic_load(&flags[tid * 16], __ATOMIC_RELAXED, __HIP_MEMORY_SCOPE_AGENT) < gen) {
        if (++spin > 4000000) { s_dead = 1; break; }   // anti-hang bailout
      }
    }
    __syncthreads();
    __threadfence();
  };

  // ---------------- prologue 1: scalars, A -> registers, ||A_:,j||^2 partials ----
  if (tid == 0) {
    s_scal[0] = sigp[0]; s_scal[1] = rhop[0]; s_scal[2] = alp[0];
    s_scal[3] = gcp[0];  s_scal[4] = gbp[0];
    s_dead = 0;
  }
  {
    float accv[JPT];
#pragma unroll
    for (int k = 0; k < JPT; ++k) accv[k] = 0.f;
#pragma unroll
    for (int r = 0; r < ROWS; ++r) {
      const float* ap = A + (size_t)(row0 + r) * NDIM + j0;
      const float4 a0 = *(const float4*)(ap);
      const float4 a1 = *(const float4*)(ap + 4);
      areg[r][0] = a0.x; areg[r][1] = a0.y; areg[r][2] = a0.z; areg[r][3] = a0.w;
      areg[r][4] = a1.x; areg[r][5] = a1.y; areg[r][6] = a1.z; areg[r][7] = a1.w;
#pragma unroll
      for (int k = 0; k < JPT; ++k) accv[k] += areg[r][k] * areg[r][k];
    }
    float* dst = P + (size_t)w * NDIM + j0;
    *(float4*)(dst)     = make_float4(accv[0], accv[1], accv[2], accv[3]);
    *(float4*)(dst + 4) = make_float4(accv[4], accv[5], accv[6], accv[7]);
  }
  __syncthreads();
  if (tid < ROWS) {
    const float gb = s_scal[4];
    zb[tid] = 0.f; yb[tid] = 0.f;
    const float ee = evec[row0 + tid];
    lbs[tid] = gb * ee * lbv[row0 + tid];
    ubs[tid] = gb * ee * ubv[row0 + tid];
  }
  if (tid < 16) {
    xa[tid] = 0.f;
    xt_g[w * 16 + tid] = 0.f;
    cs[tid] = s_scal[3] * dvec[w * 16 + tid] * cvec[w * 16 + tid];
  }
  gridbar();   // gen 1

  const float sig = s_scal[0], rho = s_scal[1], al = s_scal[2];

  // ---------------- prologue B: Mdiag; right = -c_s; r0, z0, rz0 -----------------
  {
    const int g = tid >> 4, jl = tid & 15;
    float ps = 0.f;
#pragma unroll
    for (int q = 0; q < 8; ++q) ps += P[(size_t)(g * 8 + q) * NDIM + w * 16 + jl];
    sredA[g][jl] = ps;
    __syncthreads();
    if (tid < 16) {
      float S = 0.f;
#pragma unroll
      for (int q = 0; q < 32; ++q) S += sredA[q][tid];
      Md[tid] = sig + rho * S;
      const float r0 = -cs[tid];
      r_l[tid] = r0;
      const float z0 = r0 / Md[tid];
      z_g[w * 16 + tid] = z0;
      float rzv = r0 * z0;
      rzv += __shfl_xor(rzv, 1, 64);
      rzv += __shfl_xor(rzv, 2, 64);
      rzv += __shfl_xor(rzv, 4, 64);
      rzv += __shfl_xor(rzv, 8, 64);
      if (tid == 0) rzp[w * 16] = rzv;
    }
  }
  gridbar();   // gen 2

  // ---------------- main loop ----------------------------------------------------
  for (int admm = 0; admm < N_ADMM; ++admm) {
    for (int cg = 0; cg < N_CG; ++cg) {
      // ---- phase 1: beta, p update, t = A p (own rows), outer partials, pKp ----
      {
        float v = (tid < NWG) ? rzp[tid * 16] : 0.f;
        float rs = wred64(v);
        if ((tid & 63) == 0) s_r8[tid >> 6] = rs;
        __syncthreads();
        if (tid == 0) {
          float s = 0.f;
#pragma unroll
          for (int i = 0; i < 8; ++i) s += s_r8[i];
          s_b[0] = (cg == 0) ? 0.f : (s / s_rz[0]);
          s_rz[0] = s;                       // rz_{k-1}, used for alpha in phase 2
        }
        __syncthreads();
        const float beta = s_b[0];
        const float* zp = z_g + j0;
        const float4 zv0 = *(const float4*)(zp);
        const float4 zv1 = *(const float4*)(zp + 4);
        float zl[JPT] = {zv0.x, zv0.y, zv0.z, zv0.w, zv1.x, zv1.y, zv1.z, zv1.w};
        if (cg == 0) {
#pragma unroll
          for (int k = 0; k < JPT; ++k) preg[k] = zl[k];
        } else {
#pragma unroll
          for (int k = 0; k < JPT; ++k) preg[k] = zl[k] + beta * preg[k];
        }
        if ((tid >> 1) == w) {               // stash own 16-col chunk of p
          const int b = (tid & 1) * JPT;
#pragma unroll
          for (int k = 0; k < JPT; ++k) pchunk[b + k] = preg[k];
        }
        float dp[ROWS];
#pragma unroll
        for (int r = 0; r < ROWS; ++r) {
          float s = 0.f;
#pragma unroll
          for (int k = 0; k < JPT; ++k) s += areg[r][k] * preg[k];
          dp[r] = s;
        }
#pragma unroll
        for (int r = 0; r < ROWS; ++r) {
          const float t = wred64(dp[r]);
          if ((tid & 63) == 0) dred[tid >> 6][r] = t;
        }
        __syncthreads();
        if (tid < ROWS) {
          float s = 0.f;
#pragma unroll
          for (int q = 0; q < 8; ++q) s += dred[q][tid];
          tvec[tid] = s;
        }
        __syncthreads();
        if (tid == 0) {                      // pKp partial = rho*||t_own||^2 + sig*||p_chunk||^2
          float st = 0.f;
#pragma unroll
          for (int r = 0; r < ROWS; ++r) st += tvec[r] * tvec[r];
          float sp = 0.f;
#pragma unroll
          for (int l = 0; l < 16; ++l) sp += pchunk[l] * pchunk[l];
          pkp[w * 16] = rho * st + sig * sp;
        }
        float accv[JPT];                     // outer: sum_i t_i * A[i][j]
#pragma unroll
        for (int k = 0; k < JPT; ++k) {
          float s = 0.f;
#pragma unroll
          for (int r = 0; r < ROWS; ++r) s += tvec[r] * areg[r][k];
          accv[k] = s;
        }
        float* dst = P + (size_t)w * NDIM + j0;
        *(float4*)(dst)     = make_float4(accv[0], accv[1], accv[2], accv[3]);
        *(float4*)(dst + 4) = make_float4(accv[4], accv[5], accv[6], accv[7]);
      }
      gridbar();
      // ---- phase 2: alpha, Kp (reduce), x/r/z updates, rz partials --------------
      {
        float v = (tid < NWG) ? pkp[tid * 16] : 0.f;
        float rs = wred64(v);
        if ((tid & 63) == 0) s_r8[tid >> 6] = rs;
        __syncthreads();
        if (tid == 0) {
          float s = 0.f;
#pragma unroll
          for (int i = 0; i < 8; ++i) s += s_r8[i];
          s_b[0] = s_rz[0] / s;              // alpha
        }
        __syncthreads();
        const float a = s_b[0];
        const int g = tid >> 4, jl = tid & 15;
        float ps = 0.f;
#pragma unroll
        for (int q = 0; q < 8; ++q) ps += P[(size_t)(g * 8 + q) * NDIM + w * 16 + jl];
        sredA[g][jl] = ps;
        __syncthreads();
        if (tid < 16) {
          float S = 0.f;
#pragma unroll
          for (int q = 0; q < 32; ++q) S += sredA[q][tid];
          const float Kp = rho * S + sig * pchunk[tid];
          const float rn = r_l[tid] - a * Kp;
          r_l[tid] = rn;
          xt_g[w * 16 + tid] += a * pchunk[tid];
          const float zz = rn / Md[tid];
          z_g[w * 16 + tid] = zz;
          float rzv = rn * zz;
          rzv += __shfl_xor(rzv, 1, 64);
          rzv += __shfl_xor(rzv, 2, 64);
          rzv += __shfl_xor(rzv, 4, 64);
          rzv += __shfl_xor(rzv, 8, 64);
          if (tid == 0) rzp[w * 16] = rzv;
        }
      }
      gridbar();
    }
    if (admm < N_ADMM - 1) {
      // ---- phase A': ztilde = A xt; z,y,x updates; outers for next right + Kop(xt)
      {
        const float* xp = xt_g + j0;
        const float4 xv0 = *(const float4*)(xp);
        const float4 xv1 = *(const float4*)(xp + 4);
        float xl[JPT] = {xv0.x, xv0.y, xv0.z, xv0.w, xv1.x, xv1.y, xv1.z, xv1.w};
        float dp[ROWS];
#pragma unroll
        for (int r = 0; r < ROWS; ++r) {
          float s = 0.f;
#pragma unroll
          for (int k = 0; k < JPT; ++k) s += areg[r][k] * xl[k];
          dp[r] = s;
        }
#pragma unroll
        for (int r = 0; r < ROWS; ++r) {
          const float t = wred64(dp[r]);
          if ((tid & 63) == 0) dred[tid >> 6][r] = t;
        }
        __syncthreads();
        if (tid < ROWS) {
          float s = 0.f;
#pragma unroll
          for (int q = 0; q < 8; ++q) s += dred[q][tid];
          tvec[tid] = s;                      // raw ztilde_i (also t0 for Kop(xt))
          const float zt = al * s + (1.f - al) * zb[tid];
          float zn = zt + yb[tid] / rho;
          zn = fminf(fmaxf(zn, lbs[tid]), ubs[tid]);
          const float yn = yb[tid] + rho * (zt - zn);
          zb[tid] = zn; yb[tid] = yn;
          uvec[tid] = rho * zn - yn;
        }
        if ((tid >> 1) == w) {                // x = al*xt + (1-al)*x on own chunk
          const int b = (tid & 1) * JPT;
#pragma unroll
          for (int k = 0; k < JPT; ++k) xa[b + k] = al * xl[k] + (1.f - al) * xa[b + k];
        }
        __syncthreads();
        float aK[JPT], aR[JPT];
#pragma unroll
        for (int k = 0; k < JPT; ++k) {
          float sk = 0.f, sr = 0.f;
#pragma unroll
          for (int r = 0; r < ROWS; ++r) {
            sk += tvec[r] * areg[r][k];
            sr += uvec[r] * areg[r][k];
          }
          aK[k] = sk; aR[k] = sr;
        }
        float* dk = P + (size_t)w * NDIM + j0;
        *(float4*)(dk)     = make_float4(aK[0], aK[1], aK[2], aK[3]);
        *(float4*)(dk + 4) = make_float4(aK[4], aK[5], aK[6], aK[7]);
        float* dr = R + (size_t)w * NDIM + j0;
        *(float4*)(dr)     = make_float4(aR[0], aR[1], aR[2], aR[3]);
        *(float4*)(dr + 4) = make_float4(aR[4], aR[5], aR[6], aR[7]);
      }
      gridbar();
      // ---- phase B: right-side assembly; r0, z0, rz0 ---------------------------
      {
        const int g = tid >> 4, jl = tid & 15;
        float pk = 0.f, pr = 0.f;
#pragma unroll
        for (int q = 0; q < 8; ++q) {
          const size_t off = (size_t)(g * 8 + q) * NDIM + w * 16 + jl;
          pk += P[off]; pr += R[off];
        }
        sredA[g][jl] = pk; sredB[g][jl] = pr;
        __syncthreads();
        if (tid < 16) {
          float SK = 0.f, SR = 0.f;
#pragma unroll
          for (int q = 0; q < 32; ++q) { SK += sredA[q][tid]; SR += sredB[q][tid]; }
          const float right = sig * xa[tid] - cs[tid] + SR;
          const float Kx = rho * SK + sig * xt_g[w * 16 + tid];
          const float r0 = right - Kx;
          r_l[tid] = r0;
          const float z0 = r0 / Md[tid];
          z_g[w * 16 + tid] = z0;
          float rzv = r0 * z0;
          rzv += __shfl_xor(rzv, 1, 64);
          rzv += __shfl_xor(rzv, 2, 64);
          rzv += __shfl_xor(rzv, 4, 64);
          rzv += __shfl_xor(rzv, 8, 64);
          if (tid == 0) rzp[w * 16] = rzv;
        }
      }
      gridbar();
    }
  }
  // ---------------- final: x = al*xt + (1-al)*x ; out = x * d / gb ---------------
  if (tid < 16) {
    const float gb = s_scal[4];
    const float xf = al * xt_g[w * 16 + tid] + (1.f - al) * xa[tid];
    out[w * 16 + tid] = xf * dvec[w * 16 + tid] / gb;
  }
}

extern "C" void kernel_launch(void* const* d_in, const int* in_sizes, int n_in,
                              void* d_out, int out_size, void* d_ws, size_t ws_size,
                              hipStream_t stream) {
  const float* A   = (const float*)d_in[0];
  const float* c   = (const float*)d_in[1];
  const float* lb  = (const float*)d_in[2];
  const float* ub  = (const float*)d_in[3];
  const float* dv  = (const float*)d_in[4];
  const float* ev  = (const float*)d_in[5];
  const float* gc  = (const float*)d_in[6];
  const float* gb  = (const float*)d_in[7];
  const float* rho = (const float*)d_in[8];
  const float* sg  = (const float*)d_in[9];
  const float* al  = (const float*)d_in[10];
  float* out = (float*)d_out;
  unsigned char* ws = (unsigned char*)d_ws;

  // zero the grid-barrier flags (first 16 KB of workspace) every call
  hipMemsetAsync(d_ws, 0, 1u << 14, stream);

  admm_lp_kernel<<<dim3(NWG), dim3(NT), 0, stream>>>(
      A, c, lb, ub, dv, ev, gc, gb, rho, sg, al, out, ws);
}

// Round 3
// 14134.138 us; speedup vs baseline: 5.9823x; 5.9823x over previous
//
#include <hip/hip_runtime.h>

#define NWG 256
#define NT  512
#define ROWS 8
#define JPT 8
#define NDIM 4096
#define N_ADMM 30
#define N_CG 15

static_assert(NWG * ROWS == 2048, "row partition");
static_assert(NT * JPT == NDIM, "col partition");

__device__ __forceinline__ float wred64(float v) {
#pragma unroll
  for (int m = 32; m > 0; m >>= 1) v += __shfl_xor(v, m, 64);
  return v;
}

__global__ __launch_bounds__(NT)
void admm_lp_kernel(const float* __restrict__ A, const float* __restrict__ cvec,
                    const float* __restrict__ lbv, const float* __restrict__ ubv,
                    const float* __restrict__ dvec, const float* __restrict__ evec,
                    const float* __restrict__ gcp, const float* __restrict__ gbp,
                    const float* __restrict__ rhop, const float* __restrict__ sigp,
                    const float* __restrict__ alp,
                    float* __restrict__ out, unsigned char* __restrict__ ws)
{
  const int tid = threadIdx.x;
  const int w = blockIdx.x;
  const int j0 = tid * JPT;        // this thread's column base (global)
  const int row0 = w * ROWS;       // this WG's first row

  unsigned* cnt  = (unsigned*)(ws);                        // arrival counter (line 0)
  unsigned* rel  = (unsigned*)(ws + 256);                  // release word
  unsigned* kill = (unsigned*)(ws + 512);                  // global abort flag
  float* pkp  = (float*)(ws + (1u << 14));                 // 256 * 64B padded
  float* rzp  = (float*)(ws + (2u << 14));
  float* z_g  = (float*)(ws + (3u << 14));                 // 4096 f32
  float* xt_g = (float*)(ws + (4u << 14));                 // 4096 f32
  float* P    = (float*)(ws + (5u << 14));                 // [256][4096] f32
  float* R    = (float*)(ws + (5u << 14) + (size_t)NWG * NDIM * 4);

  __shared__ float s_scal[6];
  __shared__ float s_r8[8];
  __shared__ float s_b[1];
  __shared__ float s_rz[1];
  __shared__ float dred[8][ROWS];
  __shared__ float tvec[ROWS];
  __shared__ float zb[ROWS], yb[ROWS], lbs[ROWS], ubs[ROWS], uvec[ROWS];
  __shared__ float xa[16], cs[16], Md[16], r_l[16], pchunk[16];
  __shared__ float sredA[32][16], sredB[32][16];
  __shared__ int s_dead;

  float areg[ROWS][JPT];   // this thread's slice of A (registers)
  float preg[JPT];         // this thread's slice of CG's p

  unsigned gen = 0;

  // Centralized counting barrier: one atomicAdd per WG, one spinning lane per
  // WG on a single release line. ACQ_REL/RELEASE/ACQUIRE at agent scope carry
  // cross-XCD visibility. A global kill switch bounds worst-case hang: any WG
  // that times out (~160ms) aborts EVERY WG within ~0.1ms, so a failure shows
  // up as a fast absmax error, never an unresponsive container.
  auto gridbar = [&]() {
    ++gen;
    __syncthreads();
    if (tid == 0 && !s_dead) {
      unsigned prev = __hip_atomic_fetch_add(cnt, 1u, __ATOMIC_ACQ_REL,
                                             __HIP_MEMORY_SCOPE_AGENT);
      if (prev == gen * NWG - 1u) {
        __hip_atomic_store(rel, gen, __ATOMIC_RELEASE, __HIP_MEMORY_SCOPE_AGENT);
      } else {
        int spin = 0;
        for (;;) {
          if (__hip_atomic_load(rel, __ATOMIC_RELAXED,
                                __HIP_MEMORY_SCOPE_AGENT) >= gen) break;
          __builtin_amdgcn_s_sleep(2);
          if ((++spin & 1023) == 0) {
            if (__hip_atomic_load(kill, __ATOMIC_RELAXED,
                                  __HIP_MEMORY_SCOPE_AGENT) != 0u ||
                spin > 3000000) {
              s_dead = 1;
              __hip_atomic_store(kill, 1u, __ATOMIC_RELAXED,
                                 __HIP_MEMORY_SCOPE_AGENT);
              break;
            }
          }
        }
        (void)__hip_atomic_load(rel, __ATOMIC_ACQUIRE, __HIP_MEMORY_SCOPE_AGENT);
      }
    }
    __syncthreads();
  };

  // ---------------- prologue 1: scalars, A -> registers, ||A_:,j||^2 partials ----
  if (tid == 0) {
    s_scal[0] = sigp[0]; s_scal[1] = rhop[0]; s_scal[2] = alp[0];
    s_scal[3] = gcp[0];  s_scal[4] = gbp[0];
    s_dead = 0;
  }
  {
    float accv[JPT];
#pragma unroll
    for (int k = 0; k < JPT; ++k) accv[k] = 0.f;
#pragma unroll
    for (int r = 0; r < ROWS; ++r) {
      const float* ap = A + (size_t)(row0 + r) * NDIM + j0;
      const float4 a0 = *(const float4*)(ap);
      const float4 a1 = *(const float4*)(ap + 4);
      areg[r][0] = a0.x; areg[r][1] = a0.y; areg[r][2] = a0.z; areg[r][3] = a0.w;
      areg[r][4] = a1.x; areg[r][5] = a1.y; areg[r][6] = a1.z; areg[r][7] = a1.w;
#pragma unroll
      for (int k = 0; k < JPT; ++k) accv[k] += areg[r][k] * areg[r][k];
    }
    float* dst = P + (size_t)w * NDIM + j0;
    *(float4*)(dst)     = make_float4(accv[0], accv[1], accv[2], accv[3]);
    *(float4*)(dst + 4) = make_float4(accv[4], accv[5], accv[6], accv[7]);
  }
  __syncthreads();
  if (tid < ROWS) {
    const float gb = s_scal[4];
    zb[tid] = 0.f; yb[tid] = 0.f;
    const float ee = evec[row0 + tid];
    lbs[tid] = gb * ee * lbv[row0 + tid];
    ubs[tid] = gb * ee * ubv[row0 + tid];
  }
  if (tid < 16) {
    xa[tid] = 0.f;
    xt_g[w * 16 + tid] = 0.f;
    cs[tid] = s_scal[3] * dvec[w * 16 + tid] * cvec[w * 16 + tid];
  }
  gridbar();   // gen 1

  const float sig = s_scal[0], rho = s_scal[1], al = s_scal[2];

  // ---------------- prologue B: Mdiag; right = -c_s; r0, z0, rz0 -----------------
  {
    const int g = tid >> 4, jl = tid & 15;
    float ps = 0.f;
#pragma unroll
    for (int q = 0; q < 8; ++q) ps += P[(size_t)(g * 8 + q) * NDIM + w * 16 + jl];
    sredA[g][jl] = ps;
    __syncthreads();
    if (tid < 16) {
      float S = 0.f;
#pragma unroll
      for (int q = 0; q < 32; ++q) S += sredA[q][tid];
      Md[tid] = sig + rho * S;
      const float r0 = -cs[tid];
      r_l[tid] = r0;
      const float z0 = r0 / Md[tid];
      z_g[w * 16 + tid] = z0;
      float rzv = r0 * z0;
      rzv += __shfl_xor(rzv, 1, 64);
      rzv += __shfl_xor(rzv, 2, 64);
      rzv += __shfl_xor(rzv, 4, 64);
      rzv += __shfl_xor(rzv, 8, 64);
      if (tid == 0) rzp[w * 16] = rzv;
    }
  }
  gridbar();   // gen 2

  // ---------------- main loop ----------------------------------------------------
  for (int admm = 0; admm < N_ADMM; ++admm) {
    for (int cg = 0; cg < N_CG; ++cg) {
      // ---- phase 1: beta, p update, t = A p (own rows), outer partials, pKp ----
      {
        float v = (tid < NWG) ? rzp[tid * 16] : 0.f;
        float rs = wred64(v);
        if ((tid & 63) == 0) s_r8[tid >> 6] = rs;
        __syncthreads();
        if (tid == 0) {
          float s = 0.f;
#pragma unroll
          for (int i = 0; i < 8; ++i) s += s_r8[i];
          s_b[0] = (cg == 0) ? 0.f : (s / s_rz[0]);
          s_rz[0] = s;                       // rz_{k-1}, used for alpha in phase 2
        }
        __syncthreads();
        const float beta = s_b[0];
        const float* zp = z_g + j0;
        const float4 zv0 = *(const float4*)(zp);
        const float4 zv1 = *(const float4*)(zp + 4);
        float zl[JPT] = {zv0.x, zv0.y, zv0.z, zv0.w, zv1.x, zv1.y, zv1.z, zv1.w};
        if (cg == 0) {
#pragma unroll
          for (int k = 0; k < JPT; ++k) preg[k] = zl[k];
        } else {
#pragma unroll
          for (int k = 0; k < JPT; ++k) preg[k] = zl[k] + beta * preg[k];
        }
        if ((tid >> 1) == w) {               // stash own 16-col chunk of p
          const int b = (tid & 1) * JPT;
#pragma unroll
          for (int k = 0; k < JPT; ++k) pchunk[b + k] = preg[k];
        }
        float dp[ROWS];
#pragma unroll
        for (int r = 0; r < ROWS; ++r) {
          float s = 0.f;
#pragma unroll
          for (int k = 0; k < JPT; ++k) s += areg[r][k] * preg[k];
          dp[r] = s;
        }
#pragma unroll
        for (int r = 0; r < ROWS; ++r) {
          const float t = wred64(dp[r]);
          if ((tid & 63) == 0) dred[tid >> 6][r] = t;
        }
        __syncthreads();
        if (tid < ROWS) {
          float s = 0.f;
#pragma unroll
          for (int q = 0; q < 8; ++q) s += dred[q][tid];
          tvec[tid] = s;
        }
        __syncthreads();
        if (tid == 0) {                      // pKp partial = rho*||t_own||^2 + sig*||p_chunk||^2
          float st = 0.f;
#pragma unroll
          for (int r = 0; r < ROWS; ++r) st += tvec[r] * tvec[r];
          float sp = 0.f;
#pragma unroll
          for (int l = 0; l < 16; ++l) sp += pchunk[l] * pchunk[l];
          pkp[w * 16] = rho * st + sig * sp;
        }
        float accv[JPT];                     // outer: sum_i t_i * A[i][j]
#pragma unroll
        for (int k = 0; k < JPT; ++k) {
          float s = 0.f;
#pragma unroll
          for (int r = 0; r < ROWS; ++r) s += tvec[r] * areg[r][k];
          accv[k] = s;
        }
        float* dst = P + (size_t)w * NDIM + j0;
        *(float4*)(dst)     = make_float4(accv[0], accv[1], accv[2], accv[3]);
        *(float4*)(dst + 4) = make_float4(accv[4], accv[5], accv[6], accv[7]);
      }
      gridbar();
      // ---- phase 2: alpha, Kp (reduce), x/r/z updates, rz partials --------------
      {
        float v = (tid < NWG) ? pkp[tid * 16] : 0.f;
        float rs = wred64(v);
        if ((tid & 63) == 0) s_r8[tid >> 6] = rs;
        __syncthreads();
        if (tid == 0) {
          float s = 0.f;
#pragma unroll
          for (int i = 0; i < 8; ++i) s += s_r8[i];
          s_b[0] = s_rz[0] / s;              // alpha
        }
        __syncthreads();
        const float a = s_b[0];
        const int g = tid >> 4, jl = tid & 15;
        float ps = 0.f;
#pragma unroll
        for (int q = 0; q < 8; ++q) ps += P[(size_t)(g * 8 + q) * NDIM + w * 16 + jl];
        sredA[g][jl] = ps;
        __syncthreads();
        if (tid < 16) {
          float S = 0.f;
#pragma unroll
          for (int q = 0; q < 32; ++q) S += sredA[q][tid];
          const float Kp = rho * S + sig * pchunk[tid];
          const float rn = r_l[tid] - a * Kp;
          r_l[tid] = rn;
          xt_g[w * 16 + tid] += a * pchunk[tid];
          const float zz = rn / Md[tid];
          z_g[w * 16 + tid] = zz;
          float rzv = rn * zz;
          rzv += __shfl_xor(rzv, 1, 64);
          rzv += __shfl_xor(rzv, 2, 64);
          rzv += __shfl_xor(rzv, 4, 64);
          rzv += __shfl_xor(rzv, 8, 64);
          if (tid == 0) rzp[w * 16] = rzv;
        }
      }
      gridbar();
    }
    if (admm < N_ADMM - 1) {
      // ---- phase A': ztilde = A xt; z,y,x updates; outers for next right + Kop(xt)
      {
        const float* xp = xt_g + j0;
        const float4 xv0 = *(const float4*)(xp);
        const float4 xv1 = *(const float4*)(xp + 4);
        float xl[JPT] = {xv0.x, xv0.y, xv0.z, xv0.w, xv1.x, xv1.y, xv1.z, xv1.w};
        float dp[ROWS];
#pragma unroll
        for (int r = 0; r < ROWS; ++r) {
          float s = 0.f;
#pragma unroll
          for (int k = 0; k < JPT; ++k) s += areg[r][k] * xl[k];
          dp[r] = s;
        }
#pragma unroll
        for (int r = 0; r < ROWS; ++r) {
          const float t = wred64(dp[r]);
          if ((tid & 63) == 0) dred[tid >> 6][r] = t;
        }
        __syncthreads();
        if (tid < ROWS) {
          float s = 0.f;
#pragma unroll
          for (int q = 0; q < 8; ++q) s += dred[q][tid];
          tvec[tid] = s;                      // raw ztilde_i (also t0 for Kop(xt))
          const float zt = al * s + (1.f - al) * zb[tid];
          float zn = zt + yb[tid] / rho;
          zn = fminf(fmaxf(zn, lbs[tid]), ubs[tid]);
          const float yn = yb[tid] + rho * (zt - zn);
          zb[tid] = zn; yb[tid] = yn;
          uvec[tid] = rho * zn - yn;
        }
        if ((tid >> 1) == w) {                // x = al*xt + (1-al)*x on own chunk
          const int b = (tid & 1) * JPT;
#pragma unroll
          for (int k = 0; k < JPT; ++k) xa[b + k] = al * xl[k] + (1.f - al) * xa[b + k];
        }
        __syncthreads();
        float aK[JPT], aR[JPT];
#pragma unroll
        for (int k = 0; k < JPT; ++k) {
          float sk = 0.f, sr = 0.f;
#pragma unroll
          for (int r = 0; r < ROWS; ++r) {
            sk += tvec[r] * areg[r][k];
            sr += uvec[r] * areg[r][k];
          }
          aK[k] = sk; aR[k] = sr;
        }
        float* dk = P + (size_t)w * NDIM + j0;
        *(float4*)(dk)     = make_float4(aK[0], aK[1], aK[2], aK[3]);
        *(float4*)(dk + 4) = make_float4(aK[4], aK[5], aK[6], aK[7]);
        float* dr = R + (size_t)w * NDIM + j0;
        *(float4*)(dr)     = make_float4(aR[0], aR[1], aR[2], aR[3]);
        *(float4*)(dr + 4) = make_float4(aR[4], aR[5], aR[6], aR[7]);
      }
      gridbar();
      // ---- phase B: right-side assembly; r0, z0, rz0 ---------------------------
      {
        const int g = tid >> 4, jl = tid & 15;
        float pk = 0.f, pr = 0.f;
#pragma unroll
        for (int q = 0; q < 8; ++q) {
          const size_t off = (size_t)(g * 8 + q) * NDIM + w * 16 + jl;
          pk += P[off]; pr += R[off];
        }
        sredA[g][jl] = pk; sredB[g][jl] = pr;
        __syncthreads();
        if (tid < 16) {
          float SK = 0.f, SR = 0.f;
#pragma unroll
          for (int q = 0; q < 32; ++q) { SK += sredA[q][tid]; SR += sredB[q][tid]; }
          const float right = sig * xa[tid] - cs[tid] + SR;
          const float Kx = rho * SK + sig * xt_g[w * 16 + tid];
          const float r0 = right - Kx;
          r_l[tid] = r0;
          const float z0 = r0 / Md[tid];
          z_g[w * 16 + tid] = z0;
          float rzv = r0 * z0;
          rzv += __shfl_xor(rzv, 1, 64);
          rzv += __shfl_xor(rzv, 2, 64);
          rzv += __shfl_xor(rzv, 4, 64);
          rzv += __shfl_xor(rzv, 8, 64);
          if (tid == 0) rzp[w * 16] = rzv;
        }
      }
      gridbar();
    }
  }
  // ---------------- final: x = al*xt + (1-al)*x ; out = x * d / gb ---------------
  if (tid < 16) {
    const float gb = s_scal[4];
    const float xf = al * xt_g[w * 16 + tid] + (1.f - al) * xa[tid];
    out[w * 16 + tid] = xf * dvec[w * 16 + tid] / gb;
  }
}

extern "C" void kernel_launch(void* const* d_in, const int* in_sizes, int n_in,
                              void* d_out, int out_size, void* d_ws, size_t ws_size,
                              hipStream_t stream) {
  const float* A   = (const float*)d_in[0];
  const float* c   = (const float*)d_in[1];
  const float* lb  = (const float*)d_in[2];
  const float* ub  = (const float*)d_in[3];
  const float* dv  = (const float*)d_in[4];
  const float* ev  = (const float*)d_in[5];
  const float* gc  = (const float*)d_in[6];
  const float* gb  = (const float*)d_in[7];
  const float* rho = (const float*)d_in[8];
  const float* sg  = (const float*)d_in[9];
  const float* al  = (const float*)d_in[10];
  float* out = (float*)d_out;
  unsigned char* ws = (unsigned char*)d_ws;

  // zero the barrier counter/release/kill words (first 16 KB) every call
  hipMemsetAsync(d_ws, 0, 1u << 14, stream);

  admm_lp_kernel<<<dim3(NWG), dim3(NT), 0, stream>>>(
      A, c, lb, ub, dv, ev, gc, gb, rho, sg, al, out, ws);
}

// Round 5
// 13471.277 us; speedup vs baseline: 6.2767x; 1.0492x over previous
//
#include <hip/hip_runtime.h>

#define NWG 256
#define NT  512
#define ROWS 8
#define JPT 8
#define NDIM 4096
#define N_ADMM 30
#define N_CG 15

typedef unsigned long long ull;
typedef float f32x4 __attribute__((ext_vector_type(4)));

static_assert(NWG * ROWS == 2048, "row partition");
static_assert(NT * JPT == NDIM, "col partition");

__device__ __forceinline__ float wred64(float v) {
#pragma unroll
  for (int m = 32; m > 0; m >>= 1) v += __shfl_xor(v, m, 64);
  return v;
}
__device__ __forceinline__ float wred16(float v) {
  v += __shfl_xor(v, 1, 64); v += __shfl_xor(v, 2, 64);
  v += __shfl_xor(v, 4, 64); v += __shfl_xor(v, 8, 64);
  return v;
}
__device__ __forceinline__ void nt_store4(float* p, float a, float b, float c, float d) {
  f32x4 v = {a, b, c, d};
  __builtin_nontemporal_store(v, (f32x4*)p);
}
__device__ __forceinline__ float nt_load(const float* p) {
  return __builtin_nontemporal_load(p);
}

__global__ __launch_bounds__(NT)
void admm_lp_kernel(const float* __restrict__ A, const float* __restrict__ cvec,
                    const float* __restrict__ lbv, const float* __restrict__ ubv,
                    const float* __restrict__ dvec, const float* __restrict__ evec,
                    const float* __restrict__ gcp, const float* __restrict__ gbp,
                    const float* __restrict__ rhop, const float* __restrict__ sigp,
                    const float* __restrict__ alp,
                    float* __restrict__ out, unsigned char* __restrict__ ws)
{
  const int tid = threadIdx.x;
  const int w = blockIdx.x;
  const int j0 = tid * JPT;        // this thread's column base (global)
  const int row0 = w * ROWS;       // this WG's first row

  ull* rel        = (ull*)(ws);                 // {gen, sum} release word (line 0)
  unsigned* kill  = (unsigned*)(ws + 128);      // global abort flag
  ull* flags      = (ull*)(ws + 4096);          // 256 slots, 64B stride: {gen, partial}
  float* z_g  = (float*)(ws + (1u << 15));      // 4096 f32
  float* xt_g = (float*)(ws + (1u << 15) + 16384);
  float* P    = (float*)(ws + (1u << 16));      // [256][4096] f32
  float* R    = (float*)(ws + (1u << 16) + (size_t)NWG * NDIM * 4);

  __shared__ float s_scal[6];
  __shared__ float s_r8[8];
  __shared__ float s_b[1];
  __shared__ float dred[8][ROWS];
  __shared__ float tvec[ROWS];
  __shared__ float zb[ROWS], yb[ROWS], lbs[ROWS], ubs[ROWS], uvec[ROWS];
  __shared__ float xa[16], cs[16], Md[16], r_l[16], pchunk[16], xtl[16];
  __shared__ float sredA[32][16], sredB[32][16];
  __shared__ int s_dead;

  float areg[ROWS][JPT];   // this thread's slice of A (registers)
  float preg[JPT];         // this thread's slice of CG's p

  unsigned gen = 0;

  // Fused grid-barrier + scalar-sum: each WG release-stores {gen, partial} to
  // its own line; WG0's threads 0..255 poll one line each, acquire, reduce the
  // 256 partials, and release-publish {gen, sum}; all WGs read the sum from
  // that single word. Replaces serialized same-line RMWs AND the per-WG
  // 256-line scalar gathers. Kill switch bounds worst-case hang to ~0.3 s.
  auto arrive_wait = [&](float partial) -> float {
    ++gen;
    __syncthreads();
    if (tid == 0 && !s_dead) {
      ull word = ((ull)gen << 32) | (ull)__float_as_uint(partial);
      __hip_atomic_store(&flags[(size_t)w * 8], word, __ATOMIC_RELEASE,
                         __HIP_MEMORY_SCOPE_AGENT);
    }
    if (w == 0) {
      float pv = 0.f;
      if (tid < NWG && !s_dead) {
        ull* fp = &flags[(size_t)tid * 8];
        int spin = 0;
        for (;;) {
          ull v = __hip_atomic_load(fp, __ATOMIC_RELAXED, __HIP_MEMORY_SCOPE_AGENT);
          if ((unsigned)(v >> 32) >= gen) break;
          if ((++spin & 255) == 0) {
            if (__hip_atomic_load(kill, __ATOMIC_RELAXED, __HIP_MEMORY_SCOPE_AGENT) != 0u ||
                spin > 400000) {
              s_dead = 1;
              __hip_atomic_store(kill, 1u, __ATOMIC_RELAXED, __HIP_MEMORY_SCOPE_AGENT);
              break;
            }
          }
        }
        ull v = __hip_atomic_load(fp, __ATOMIC_ACQUIRE, __HIP_MEMORY_SCOPE_AGENT);
        pv = __uint_as_float((unsigned)(v & 0xffffffffu));
      }
      if (tid < NWG) {
        float s = wred64(pv);
        if ((tid & 63) == 0) s_r8[tid >> 6] = s;
      }
      __syncthreads();
      if (tid == 0) {
        float sum = s_r8[0] + s_r8[1] + s_r8[2] + s_r8[3];
        s_b[0] = sum;
        ull word = ((ull)gen << 32) | (ull)__float_as_uint(sum);
        __hip_atomic_store(rel, word, __ATOMIC_RELEASE, __HIP_MEMORY_SCOPE_AGENT);
      }
      __syncthreads();
      return s_b[0];
    } else {
      if (tid == 0 && !s_dead) {
        int spin = 0;
        for (;;) {
          ull v = __hip_atomic_load(rel, __ATOMIC_RELAXED, __HIP_MEMORY_SCOPE_AGENT);
          if ((unsigned)(v >> 32) >= gen) break;
          __builtin_amdgcn_s_sleep(1);
          if ((++spin & 255) == 0) {
            if (__hip_atomic_load(kill, __ATOMIC_RELAXED, __HIP_MEMORY_SCOPE_AGENT) != 0u ||
                spin > 400000) {
              s_dead = 1;
              __hip_atomic_store(kill, 1u, __ATOMIC_RELAXED, __HIP_MEMORY_SCOPE_AGENT);
              break;
            }
          }
        }
        ull v = __hip_atomic_load(rel, __ATOMIC_ACQUIRE, __HIP_MEMORY_SCOPE_AGENT);
        s_b[0] = __uint_as_float((unsigned)(v & 0xffffffffu));
      }
      __syncthreads();
      return s_b[0];
    }
  };

  // ---------------- prologue 1: scalars, A -> registers, ||A_:,j||^2 partials ----
  if (tid == 0) {
    s_scal[0] = sigp[0]; s_scal[1] = rhop[0]; s_scal[2] = alp[0];
    s_scal[3] = gcp[0];  s_scal[4] = gbp[0];
    s_dead = 0;
  }
  {
    float accv[JPT];
#pragma unroll
    for (int k = 0; k < JPT; ++k) accv[k] = 0.f;
#pragma unroll
    for (int r = 0; r < ROWS; ++r) {
      const float* ap = A + (size_t)(row0 + r) * NDIM + j0;
      const float4 a0 = *(const float4*)(ap);
      const float4 a1 = *(const float4*)(ap + 4);
      areg[r][0] = a0.x; areg[r][1] = a0.y; areg[r][2] = a0.z; areg[r][3] = a0.w;
      areg[r][4] = a1.x; areg[r][5] = a1.y; areg[r][6] = a1.z; areg[r][7] = a1.w;
#pragma unroll
      for (int k = 0; k < JPT; ++k) accv[k] += areg[r][k] * areg[r][k];
    }
    float* dst = P + (size_t)w * NDIM + j0;
    nt_store4(dst,     accv[0], accv[1], accv[2], accv[3]);
    nt_store4(dst + 4, accv[4], accv[5], accv[6], accv[7]);
  }
  __syncthreads();
  if (tid < ROWS) {
    const float gb = s_scal[4];
    zb[tid] = 0.f; yb[tid] = 0.f;
    const float ee = evec[row0 + tid];
    lbs[tid] = gb * ee * lbv[row0 + tid];
    ubs[tid] = gb * ee * ubv[row0 + tid];
  }
  if (tid < 16) {
    xa[tid] = 0.f; xtl[tid] = 0.f;
    cs[tid] = s_scal[3] * dvec[w * 16 + tid] * cvec[w * 16 + tid];
  }
  (void)arrive_wait(0.f);   // gen 1

  const float sig = s_scal[0], rho = s_scal[1], al = s_scal[2];

  // ---------------- prologue B: Mdiag; right = -c_s; r0, z0, rz0 -----------------
  float rz_cur, rz_old = 1.f;
  {
    const int g = tid >> 4, jl = tid & 15;
    float ps = 0.f;
#pragma unroll
    for (int q = 0; q < 8; ++q) ps += nt_load(&P[(size_t)(g * 8 + q) * NDIM + w * 16 + jl]);
    sredA[g][jl] = ps;
    __syncthreads();
    float apart = 0.f;
    if (tid < 16) {
      float S = 0.f;
#pragma unroll
      for (int q = 0; q < 32; ++q) S += sredA[q][tid];
      Md[tid] = sig + rho * S;
      const float r0 = -cs[tid];
      r_l[tid] = r0;
      const float z0 = r0 / Md[tid];
      z_g[w * 16 + tid] = z0;
      float rzv = wred16(r0 * z0);
      if (tid == 0) apart = rzv;
    }
    rz_cur = arrive_wait(apart);   // gen 2; rz0 broadcast
  }

  // ---------------- main loop ----------------------------------------------------
  for (int admm = 0; admm < N_ADMM; ++admm) {
    for (int cg = 0; cg < N_CG; ++cg) {
      // ---- phase 1: beta local, p update, t = A p (own rows), outers, pKp ------
      float pkp_sum;
      {
        const float beta = (cg == 0) ? 0.f : (rz_cur / rz_old);
        rz_old = rz_cur;
        const float* zp = z_g + j0;
        const float4 zv0 = *(const float4*)(zp);
        const float4 zv1 = *(const float4*)(zp + 4);
        float zl[JPT] = {zv0.x, zv0.y, zv0.z, zv0.w, zv1.x, zv1.y, zv1.z, zv1.w};
        if (cg == 0) {
#pragma unroll
          for (int k = 0; k < JPT; ++k) preg[k] = zl[k];
        } else {
#pragma unroll
          for (int k = 0; k < JPT; ++k) preg[k] = zl[k] + beta * preg[k];
        }
        if ((tid >> 1) == w) {               // stash own 16-col chunk of p
          const int b = (tid & 1) * JPT;
#pragma unroll
          for (int k = 0; k < JPT; ++k) pchunk[b + k] = preg[k];
        }
        float dp[ROWS];
#pragma unroll
        for (int r = 0; r < ROWS; ++r) {
          float s = 0.f;
#pragma unroll
          for (int k = 0; k < JPT; ++k) s += areg[r][k] * preg[k];
          dp[r] = s;
        }
#pragma unroll
        for (int r = 0; r < ROWS; ++r) {
          const float t = wred64(dp[r]);
          if ((tid & 63) == 0) dred[tid >> 6][r] = t;
        }
        __syncthreads();
        if (tid < ROWS) {
          float s = 0.f;
#pragma unroll
          for (int q = 0; q < 8; ++q) s += dred[q][tid];
          tvec[tid] = s;
        }
        __syncthreads();
        float apart = 0.f;
        if (tid == 0) {                      // pKp partial
          float st = 0.f;
#pragma unroll
          for (int r = 0; r < ROWS; ++r) st += tvec[r] * tvec[r];
          float sp = 0.f;
#pragma unroll
          for (int l = 0; l < 16; ++l) sp += pchunk[l] * pchunk[l];
          apart = rho * st + sig * sp;
        }
        float accv[JPT];                     // outer: sum_i t_i * A[i][j]
#pragma unroll
        for (int k = 0; k < JPT; ++k) {
          float s = 0.f;
#pragma unroll
          for (int r = 0; r < ROWS; ++r) s += tvec[r] * areg[r][k];
          accv[k] = s;
        }
        float* dst = P + (size_t)w * NDIM + j0;
        nt_store4(dst,     accv[0], accv[1], accv[2], accv[3]);
        nt_store4(dst + 4, accv[4], accv[5], accv[6], accv[7]);
        pkp_sum = arrive_wait(apart);
      }
      // ---- phase 2: alpha local, Kp column-reduce, x/r/z updates, rz partial ----
      {
        const float a = rz_old / pkp_sum;
        const int g = tid >> 4, jl = tid & 15;
        float ps = 0.f;
#pragma unroll
        for (int q = 0; q < 8; ++q) ps += nt_load(&P[(size_t)(g * 8 + q) * NDIM + w * 16 + jl]);
        sredA[g][jl] = ps;
        __syncthreads();
        float apart = 0.f;
        if (tid < 16) {
          float S = 0.f;
#pragma unroll
          for (int q = 0; q < 32; ++q) S += sredA[q][tid];
          const float Kp = rho * S + sig * pchunk[tid];
          const float rn = r_l[tid] - a * Kp;
          r_l[tid] = rn;
          xtl[tid] += a * pchunk[tid];
          if (cg == N_CG - 1) xt_g[w * 16 + tid] = xtl[tid];
          const float zz = rn / Md[tid];
          z_g[w * 16 + tid] = zz;
          float rzv = wred16(rn * zz);
          if (tid == 0) apart = rzv;
        }
        rz_cur = arrive_wait(apart);
      }
    }
    if (admm < N_ADMM - 1) {
      // ---- phase A': ztilde = A xt; z,y,x updates; outers for next right + Kop(xt)
      {
        const float* xp = xt_g + j0;
        const float4 xv0 = *(const float4*)(xp);
        const float4 xv1 = *(const float4*)(xp + 4);
        float xl[JPT] = {xv0.x, xv0.y, xv0.z, xv0.w, xv1.x, xv1.y, xv1.z, xv1.w};
        float dp[ROWS];
#pragma unroll
        for (int r = 0; r < ROWS; ++r) {
          float s = 0.f;
#pragma unroll
          for (int k = 0; k < JPT; ++k) s += areg[r][k] * xl[k];
          dp[r] = s;
        }
#pragma unroll
        for (int r = 0; r < ROWS; ++r) {
          const float t = wred64(dp[r]);
          if ((tid & 63) == 0) dred[tid >> 6][r] = t;
        }
        __syncthreads();
        if (tid < ROWS) {
          float s = 0.f;
#pragma unroll
          for (int q = 0; q < 8; ++q) s += dred[q][tid];
          tvec[tid] = s;                      // raw ztilde_i (also t0 for Kop(xt))
          const float zt = al * s + (1.f - al) * zb[tid];
          float zn = zt + yb[tid] / rho;
          zn = fminf(fmaxf(zn, lbs[tid]), ubs[tid]);
          const float yn = yb[tid] + rho * (zt - zn);
          zb[tid] = zn; yb[tid] = yn;
          uvec[tid] = rho * zn - yn;
        }
        if ((tid >> 1) == w) {                // x = al*xt + (1-al)*x on own chunk
          const int b = (tid & 1) * JPT;
#pragma unroll
          for (int k = 0; k < JPT; ++k) xa[b + k] = al * xl[k] + (1.f - al) * xa[b + k];
        }
        __syncthreads();
        float aK[JPT], aR[JPT];
#pragma unroll
        for (int k = 0; k < JPT; ++k) {
          float sk = 0.f, sr = 0.f;
#pragma unroll
          for (int r = 0; r < ROWS; ++r) {
            sk += tvec[r] * areg[r][k];
            sr += uvec[r] * areg[r][k];
          }
          aK[k] = sk; aR[k] = sr;
        }
        float* dk = P + (size_t)w * NDIM + j0;
        nt_store4(dk,     aK[0], aK[1], aK[2], aK[3]);
        nt_store4(dk + 4, aK[4], aK[5], aK[6], aK[7]);
        float* dr = R + (size_t)w * NDIM + j0;
        nt_store4(dr,     aR[0], aR[1], aR[2], aR[3]);
        nt_store4(dr + 4, aR[4], aR[5], aR[6], aR[7]);
        (void)arrive_wait(0.f);
      }
      // ---- phase B: right-side assembly; r0, z0, rz0 ---------------------------
      {
        const int g = tid >> 4, jl = tid & 15;
        float pk = 0.f, pr = 0.f;
#pragma unroll
        for (int q = 0; q < 8; ++q) {
          const size_t off = (size_t)(g * 8 + q) * NDIM + w * 16 + jl;
          pk += nt_load(&P[off]); pr += nt_load(&R[off]);
        }
        sredA[g][jl] = pk; sredB[g][jl] = pr;
        __syncthreads();
        float apart = 0.f;
        if (tid < 16) {
          float SK = 0.f, SR = 0.f;
#pragma unroll
          for (int q = 0; q < 32; ++q) { SK += sredA[q][tid]; SR += sredB[q][tid]; }
          const float right = sig * xa[tid] - cs[tid] + SR;
          const float Kx = rho * SK + sig * xtl[tid];
          const float r0 = right - Kx;
          r_l[tid] = r0;
          const float z0 = r0 / Md[tid];
          z_g[w * 16 + tid] = z0;
          float rzv = wred16(r0 * z0);
          if (tid == 0) apart = rzv;
        }
        rz_cur = arrive_wait(apart);
      }
    }
  }
  // ---------------- final: x = al*xt + (1-al)*x ; out = x * d / gb ---------------
  if (tid < 16) {
    const float gb = s_scal[4];
    const float xf = al * xtl[tid] + (1.f - al) * xa[tid];
    out[w * 16 + tid] = xf * dvec[w * 16 + tid] / gb;
  }
}

extern "C" void kernel_launch(void* const* d_in, const int* in_sizes, int n_in,
                              void* d_out, int out_size, void* d_ws, size_t ws_size,
                              hipStream_t stream) {
  const float* A   = (const float*)d_in[0];
  const float* c   = (const float*)d_in[1];
  const float* lb  = (const float*)d_in[2];
  const float* ub  = (const float*)d_in[3];
  const float* dv  = (const float*)d_in[4];
  const float* ev  = (const float*)d_in[5];
  const float* gc  = (const float*)d_in[6];
  const float* gb  = (const float*)d_in[7];
  const float* rho = (const float*)d_in[8];
  const float* sg  = (const float*)d_in[9];
  const float* al  = (const float*)d_in[10];
  float* out = (float*)d_out;
  unsigned char* ws = (unsigned char*)d_ws;

  // zero rel/kill/flags (first 32 KB of workspace) every call
  (void)hipMemsetAsync(d_ws, 0, 1u << 15, stream);

  admm_lp_kernel<<<dim3(NWG), dim3(NT), 0, stream>>>(
      A, c, lb, ub, dv, ev, gc, gb, rho, sg, al, out, ws);
}

// Round 6
// 8031.242 us; speedup vs baseline: 10.5282x; 1.6774x over previous
//
#include <hip/hip_runtime.h>

#define NWG 256
#define NT  512
#define ROWS 8        // rows per WG (row slice)
#define JPT 8         // cols per thread (row slice)
#define CPW 16        // cols per WG (col slice)
#define RPT 64        // rows per thread (col slice)
#define NDIM 4096
#define MROWS 2048
#define N_ADMM 30
#define N_CG 15

typedef unsigned long long ull;

static_assert(NWG * ROWS == MROWS, "row partition");
static_assert(NT * JPT == NDIM, "col partition");
static_assert(NWG * CPW == NDIM, "col-slice partition");
static_assert(32 * RPT == MROWS, "col-slice rows");

__device__ __forceinline__ float wred64(float v) {
#pragma unroll
  for (int m = 32; m > 0; m >>= 1) v += __shfl_xor(v, m, 64);
  return v;
}
__device__ __forceinline__ float wred16(float v) {
  v += __shfl_xor(v, 1, 64); v += __shfl_xor(v, 2, 64);
  v += __shfl_xor(v, 4, 64); v += __shfl_xor(v, 8, 64);
  return v;
}

__global__ __launch_bounds__(NT, 2)
void admm_lp_kernel(const float* __restrict__ A, const float* __restrict__ cvec,
                    const float* __restrict__ lbv, const float* __restrict__ ubv,
                    const float* __restrict__ dvec, const float* __restrict__ evec,
                    const float* __restrict__ gcp, const float* __restrict__ gbp,
                    const float* __restrict__ rhop, const float* __restrict__ sigp,
                    const float* __restrict__ alp,
                    float* __restrict__ out, unsigned char* __restrict__ ws)
{
  const int tid = threadIdx.x;
  const int w = blockIdx.x;
  const int j0 = tid * JPT;        // this thread's column base (row-slice work)
  const int row0 = w * ROWS;       // this WG's first row
  const int g = tid >> 4;          // col-slice row group 0..31
  const int l = tid & 15;          // col-slice column 0..15 (global col w*16+l)

  ull* rel        = (ull*)(ws);                 // {gen, sum} release word
  unsigned* kill  = (unsigned*)(ws + 128);      // global abort flag
  ull* flags      = (ull*)(ws + 4096);          // 256 slots, 64B stride
  float* z_g  = (float*)(ws + 32768);           // 4096 f32
  float* xt_g = (float*)(ws + 32768 + 16384);   // 4096 f32
  float* t_g  = (float*)(ws + 65536);           // 2048 f32
  float* u_g  = (float*)(ws + 65536 + 8192);    // 2048 f32

  __shared__ float s_scal[6];
  __shared__ float s_r8[8];
  __shared__ float s_b[1];
  __shared__ float dred[8][ROWS];
  __shared__ float tvec[ROWS];
  __shared__ float zb[ROWS], yb[ROWS], lbs[ROWS], ubs[ROWS];
  __shared__ float xa[16], cs[16], Md[16], r_l[16], pchunk[16], xtl[16];
  __shared__ float sredA[32][16], sredB[32][16];
  __shared__ int s_dead;

  float areg[ROWS][JPT];   // 64 VGPR: row slice of A
  float acol[RPT];         // 64 VGPR: col slice of A (rows g*64.., col w*16+l)
  float preg[JPT];         // col slice of CG's p

  unsigned gen = 0;

  // Fused grid-barrier + scalar-sum (R5 protocol, proven correct): parallel
  // per-WG release flags; WG0 aggregates + publishes {gen,sum}; kill switch
  // bounds worst-case hang to ~0.3 s.
  auto arrive_wait = [&](float partial) -> float {
    ++gen;
    __syncthreads();
    if (tid == 0 && !s_dead) {
      ull word = ((ull)gen << 32) | (ull)__float_as_uint(partial);
      __hip_atomic_store(&flags[(size_t)w * 8], word, __ATOMIC_RELEASE,
                         __HIP_MEMORY_SCOPE_AGENT);
    }
    if (w == 0) {
      float pv = 0.f;
      if (tid < NWG && !s_dead) {
        ull* fp = &flags[(size_t)tid * 8];
        int spin = 0;
        for (;;) {
          ull v = __hip_atomic_load(fp, __ATOMIC_RELAXED, __HIP_MEMORY_SCOPE_AGENT);
          if ((unsigned)(v >> 32) >= gen) break;
          if ((++spin & 255) == 0) {
            if (__hip_atomic_load(kill, __ATOMIC_RELAXED, __HIP_MEMORY_SCOPE_AGENT) != 0u ||
                spin > 400000) {
              s_dead = 1;
              __hip_atomic_store(kill, 1u, __ATOMIC_RELAXED, __HIP_MEMORY_SCOPE_AGENT);
              break;
            }
          }
        }
        ull v = __hip_atomic_load(fp, __ATOMIC_ACQUIRE, __HIP_MEMORY_SCOPE_AGENT);
        pv = __uint_as_float((unsigned)(v & 0xffffffffu));
      }
      if (tid < NWG) {
        float s = wred64(pv);
        if ((tid & 63) == 0) s_r8[tid >> 6] = s;
      }
      __syncthreads();
      if (tid == 0) {
        float sum = s_r8[0] + s_r8[1] + s_r8[2] + s_r8[3];
        s_b[0] = sum;
        ull word = ((ull)gen << 32) | (ull)__float_as_uint(sum);
        __hip_atomic_store(rel, word, __ATOMIC_RELEASE, __HIP_MEMORY_SCOPE_AGENT);
      }
      __syncthreads();
      return s_b[0];
    } else {
      if (tid == 0 && !s_dead) {
        int spin = 0;
        for (;;) {
          ull v = __hip_atomic_load(rel, __ATOMIC_RELAXED, __HIP_MEMORY_SCOPE_AGENT);
          if ((unsigned)(v >> 32) >= gen) break;
          __builtin_amdgcn_s_sleep(1);
          if ((++spin & 255) == 0) {
            if (__hip_atomic_load(kill, __ATOMIC_RELAXED, __HIP_MEMORY_SCOPE_AGENT) != 0u ||
                spin > 400000) {
              s_dead = 1;
              __hip_atomic_store(kill, 1u, __ATOMIC_RELAXED, __HIP_MEMORY_SCOPE_AGENT);
              break;
            }
          }
        }
        ull v = __hip_atomic_load(rel, __ATOMIC_ACQUIRE, __HIP_MEMORY_SCOPE_AGENT);
        s_b[0] = __uint_as_float((unsigned)(v & 0xffffffffu));
      }
      __syncthreads();
      return s_b[0];
    }
  };

  // ---------------- prologue: scalars, A row-slice + col-slice, col norms -------
  if (tid == 0) {
    s_scal[0] = sigp[0]; s_scal[1] = rhop[0]; s_scal[2] = alp[0];
    s_scal[3] = gcp[0];  s_scal[4] = gbp[0];
    s_dead = 0;
  }
  {
#pragma unroll
    for (int r = 0; r < ROWS; ++r) {
      const float* ap = A + (size_t)(row0 + r) * NDIM + j0;
      const float4 a0 = *(const float4*)(ap);
      const float4 a1 = *(const float4*)(ap + 4);
      areg[r][0] = a0.x; areg[r][1] = a0.y; areg[r][2] = a0.z; areg[r][3] = a0.w;
      areg[r][4] = a1.x; areg[r][5] = a1.y; areg[r][6] = a1.z; areg[r][7] = a1.w;
    }
    float cn = 0.f;
#pragma unroll
    for (int r = 0; r < RPT; ++r) {
      acol[r] = A[(size_t)(g * RPT + r) * NDIM + w * CPW + l];
      cn += acol[r] * acol[r];
    }
    sredA[g][l] = cn;
  }
  __syncthreads();
  if (tid < ROWS) {
    const float gb = s_scal[4];
    zb[tid] = 0.f; yb[tid] = 0.f;
    const float ee = evec[row0 + tid];
    lbs[tid] = gb * ee * lbv[row0 + tid];
    ubs[tid] = gb * ee * ubv[row0 + tid];
  }
  const float sig = s_scal[0], rho = s_scal[1], al = s_scal[2];
  float rz_cur, rz_old = 1.f;
  {
    float apart = 0.f;
    if (tid < 16) {
      xa[tid] = 0.f; xtl[tid] = 0.f;
      cs[tid] = s_scal[3] * dvec[w * 16 + tid] * cvec[w * 16 + tid];
      float S = 0.f;
#pragma unroll
      for (int q = 0; q < 32; ++q) S += sredA[q][tid];
      Md[tid] = sig + rho * S;
      const float r0 = -cs[tid];
      r_l[tid] = r0;
      const float z0 = r0 / Md[tid];
      z_g[w * 16 + tid] = z0;
      float rzv = wred16(r0 * z0);
      if (tid == 0) apart = rzv;
    }
    rz_cur = arrive_wait(apart);   // gen 1: rz0 broadcast + z_g visible
  }

  // ---------------- main loop ----------------------------------------------------
  for (int admm = 0; admm < N_ADMM; ++admm) {
    for (int cg = 0; cg < N_CG; ++cg) {
      // ---- phase 1: beta, p update, t = A p (own rows) -> t_g, pKp partial -----
      float pkp_sum;
      {
        const float beta = (cg == 0) ? 0.f : (rz_cur / rz_old);
        rz_old = rz_cur;
        const float* zp = z_g + j0;
        const float4 zv0 = *(const float4*)(zp);
        const float4 zv1 = *(const float4*)(zp + 4);
        float zl[JPT] = {zv0.x, zv0.y, zv0.z, zv0.w, zv1.x, zv1.y, zv1.z, zv1.w};
        if (cg == 0) {
#pragma unroll
          for (int k = 0; k < JPT; ++k) preg[k] = zl[k];
        } else {
#pragma unroll
          for (int k = 0; k < JPT; ++k) preg[k] = zl[k] + beta * preg[k];
        }
        if ((tid >> 1) == w) {               // stash own 16-col chunk of p
          const int b = (tid & 1) * JPT;
#pragma unroll
          for (int k = 0; k < JPT; ++k) pchunk[b + k] = preg[k];
        }
        float dp[ROWS];
#pragma unroll
        for (int r = 0; r < ROWS; ++r) {
          float s = 0.f;
#pragma unroll
          for (int k = 0; k < JPT; ++k) s += areg[r][k] * preg[k];
          dp[r] = s;
        }
#pragma unroll
        for (int r = 0; r < ROWS; ++r) {
          const float t = wred64(dp[r]);
          if ((tid & 63) == 0) dred[tid >> 6][r] = t;
        }
        __syncthreads();
        if (tid < ROWS) {
          float s = 0.f;
#pragma unroll
          for (int q = 0; q < 8; ++q) s += dred[q][tid];
          tvec[tid] = s;
          t_g[row0 + tid] = s;               // publish own t rows (8 floats)
        }
        __syncthreads();
        float apart = 0.f;
        if (tid == 0) {                      // pKp partial
          float st = 0.f;
#pragma unroll
          for (int r = 0; r < ROWS; ++r) st += tvec[r] * tvec[r];
          float sp = 0.f;
#pragma unroll
          for (int li = 0; li < 16; ++li) sp += pchunk[li] * pchunk[li];
          apart = rho * st + sig * sp;
        }
        pkp_sum = arrive_wait(apart);
      }
      // ---- phase 2: u = A^T t via col slice, x/r/z updates, rz partial ----------
      {
        const float a = rz_old / pkp_sum;
        const float4* t4 = (const float4*)t_g;
        float part = 0.f;
#pragma unroll
        for (int r4 = 0; r4 < RPT / 4; ++r4) {
          const float4 tv = t4[g * (RPT / 4) + r4];
          part += tv.x * acol[r4 * 4 + 0] + tv.y * acol[r4 * 4 + 1]
                + tv.z * acol[r4 * 4 + 2] + tv.w * acol[r4 * 4 + 3];
        }
        sredA[g][l] = part;
        __syncthreads();
        float apart = 0.f;
        if (tid < 16) {
          float S = 0.f;
#pragma unroll
          for (int q = 0; q < 32; ++q) S += sredA[q][tid];
          const float Kp = rho * S + sig * pchunk[tid];
          const float rn = r_l[tid] - a * Kp;
          r_l[tid] = rn;
          xtl[tid] += a * pchunk[tid];
          if (cg == N_CG - 1) xt_g[w * 16 + tid] = xtl[tid];
          const float zz = rn / Md[tid];
          z_g[w * 16 + tid] = zz;
          float rzv = wred16(rn * zz);
          if (tid == 0) apart = rzv;
        }
        rz_cur = arrive_wait(apart);
      }
    }
    if (admm < N_ADMM - 1) {
      // ---- phase A': ztilde = A xt (rows); z,y updates; publish t_g,u_g --------
      {
        const float* xp = xt_g + j0;
        const float4 xv0 = *(const float4*)(xp);
        const float4 xv1 = *(const float4*)(xp + 4);
        float xl[JPT] = {xv0.x, xv0.y, xv0.z, xv0.w, xv1.x, xv1.y, xv1.z, xv1.w};
        float dp[ROWS];
#pragma unroll
        for (int r = 0; r < ROWS; ++r) {
          float s = 0.f;
#pragma unroll
          for (int k = 0; k < JPT; ++k) s += areg[r][k] * xl[k];
          dp[r] = s;
        }
#pragma unroll
        for (int r = 0; r < ROWS; ++r) {
          const float t = wred64(dp[r]);
          if ((tid & 63) == 0) dred[tid >> 6][r] = t;
        }
        __syncthreads();
        if (tid < ROWS) {
          float s = 0.f;
#pragma unroll
          for (int q = 0; q < 8; ++q) s += dred[q][tid];
          t_g[row0 + tid] = s;                // raw ztilde rows (input to Kop(xt))
          const float zt = al * s + (1.f - al) * zb[tid];
          float zn = zt + yb[tid] / rho;
          zn = fminf(fmaxf(zn, lbs[tid]), ubs[tid]);
          const float yn = yb[tid] + rho * (zt - zn);
          zb[tid] = zn; yb[tid] = yn;
          u_g[row0 + tid] = rho * zn - yn;    // rhs row vector
        }
        if ((tid >> 1) == w) {                // x = al*xt + (1-al)*x on own chunk
          const int b = (tid & 1) * JPT;
#pragma unroll
          for (int k = 0; k < JPT; ++k) xa[b + k] = al * xl[k] + (1.f - al) * xa[b + k];
        }
        (void)arrive_wait(0.f);
      }
      // ---- phase B: right = sig*x - c + A^T u ; r0 = right - Kop(xt); rz0 ------
      {
        const float4* t4 = (const float4*)t_g;
        const float4* u4 = (const float4*)u_g;
        float pk = 0.f, pr = 0.f;
#pragma unroll
        for (int r4 = 0; r4 < RPT / 4; ++r4) {
          const float4 tv = t4[g * (RPT / 4) + r4];
          const float4 uv = u4[g * (RPT / 4) + r4];
          pk += tv.x * acol[r4 * 4 + 0] + tv.y * acol[r4 * 4 + 1]
              + tv.z * acol[r4 * 4 + 2] + tv.w * acol[r4 * 4 + 3];
          pr += uv.x * acol[r4 * 4 + 0] + uv.y * acol[r4 * 4 + 1]
              + uv.z * acol[r4 * 4 + 2] + uv.w * acol[r4 * 4 + 3];
        }
        sredA[g][l] = pk; sredB[g][l] = pr;
        __syncthreads();
        float apart = 0.f;
        if (tid < 16) {
          float SK = 0.f, SR = 0.f;
#pragma unroll
          for (int q = 0; q < 32; ++q) { SK += sredA[q][tid]; SR += sredB[q][tid]; }
          const float right = sig * xa[tid] - cs[tid] + SR;
          const float Kx = rho * SK + sig * xtl[tid];
          const float r0 = right - Kx;
          r_l[tid] = r0;
          const float z0 = r0 / Md[tid];
          z_g[w * 16 + tid] = z0;
          float rzv = wred16(r0 * z0);
          if (tid == 0) apart = rzv;
        }
        rz_cur = arrive_wait(apart);
      }
    }
  }
  // ---------------- final: x = al*xt + (1-al)*x ; out = x * d / gb ---------------
  if (tid < 16) {
    const float gb = s_scal[4];
    const float xf = al * xtl[tid] + (1.f - al) * xa[tid];
    out[w * 16 + tid] = xf * dvec[w * 16 + tid] / gb;
  }
}

extern "C" void kernel_launch(void* const* d_in, const int* in_sizes, int n_in,
                              void* d_out, int out_size, void* d_ws, size_t ws_size,
                              hipStream_t stream) {
  const float* A   = (const float*)d_in[0];
  const float* c   = (const float*)d_in[1];
  const float* lb  = (const float*)d_in[2];
  const float* ub  = (const float*)d_in[3];
  const float* dv  = (const float*)d_in[4];
  const float* ev  = (const float*)d_in[5];
  const float* gc  = (const float*)d_in[6];
  const float* gb  = (const float*)d_in[7];
  const float* rho = (const float*)d_in[8];
  const float* sg  = (const float*)d_in[9];
  const float* al  = (const float*)d_in[10];
  float* out = (float*)d_out;
  unsigned char* ws = (unsigned char*)d_ws;

  // zero rel/kill/flags (first 32 KB of workspace) every call
  (void)hipMemsetAsync(d_ws, 0, 1u << 15, stream);

  admm_lp_kernel<<<dim3(NWG), dim3(NT), 0, stream>>>(
      A, c, lb, ub, dv, ev, gc, gb, rho, sg, al, out, ws);
}

// Round 7
// 7383.915 us; speedup vs baseline: 11.4512x; 1.0877x over previous
//
#include <hip/hip_runtime.h>

#define NWG 256
#define NT  512
#define ROWS 8        // rows per WG (row slice)
#define JPT 8         // cols per thread (row slice)
#define CPW 16        // cols per WG (col slice)
#define RPT 64        // rows per thread (col slice)
#define NDIM 4096
#define MROWS 2048
#define N_ADMM 30
#define N_CG 15

typedef unsigned long long ull;

static_assert(NWG * ROWS == MROWS, "row partition");
static_assert(NT * JPT == NDIM, "col partition");
static_assert(NWG * CPW == NDIM, "col-slice partition");
static_assert(32 * RPT == MROWS, "col-slice rows");

__device__ __forceinline__ float wred64(float v) {
#pragma unroll
  for (int m = 32; m > 0; m >>= 1) v += __shfl_xor(v, m, 64);
  return v;
}
__device__ __forceinline__ float wred16(float v) {
  v += __shfl_xor(v, 1, 64); v += __shfl_xor(v, 2, 64);
  v += __shfl_xor(v, 4, 64); v += __shfl_xor(v, 8, 64);
  return v;
}

__global__ __launch_bounds__(NT, 2)
void admm_lp_kernel(const float* __restrict__ A, const float* __restrict__ cvec,
                    const float* __restrict__ lbv, const float* __restrict__ ubv,
                    const float* __restrict__ dvec, const float* __restrict__ evec,
                    const float* __restrict__ gcp, const float* __restrict__ gbp,
                    const float* __restrict__ rhop, const float* __restrict__ sigp,
                    const float* __restrict__ alp,
                    float* __restrict__ out, unsigned char* __restrict__ ws)
{
  const int tid = threadIdx.x;
  const int w = blockIdx.x;
  const int j0 = tid * JPT;        // this thread's column base (row-slice work)
  const int row0 = w * ROWS;       // this WG's first row
  const int g = tid >> 4;          // col-slice row group 0..31
  const int l = tid & 15;          // col-slice column 0..15 (global col w*16+l)

  unsigned* kill  = (unsigned*)(ws + 128);      // global abort flag
  ull* flags      = (ull*)(ws + 4096);          // 256 slots, 64B stride: {gen,partial}
  float* z_g  = (float*)(ws + 32768);           // 4096 f32
  float* xt_g = (float*)(ws + 32768 + 16384);   // 4096 f32
  float* t_g  = (float*)(ws + 65536);           // 2048 f32
  float* u_g  = (float*)(ws + 65536 + 8192);    // 2048 f32

  __shared__ float s_scal[6];
  __shared__ float s_b[1];
  __shared__ float dred[8][ROWS];
  __shared__ float tvec[ROWS];
  __shared__ float zb[ROWS], yb[ROWS], lbs[ROWS], ubs[ROWS];
  __shared__ float xa[16], cs[16], Md[16], r_l[16], pchunk[16], xtl[16];
  __shared__ float sredA[32][16], sredB[32][16];
  __shared__ int s_dead;

  float areg[ROWS][JPT];   // 64 VGPR: row slice of A
  float acol[RPT];         // 64 VGPR: col slice of A (rows g*64.., col w*16+l)
  float preg[JPT];         // col slice of CG's p

  unsigned gen = 0;

  // Single-stage fused barrier + global scalar-sum: each WG's lane 0
  // release-stores {gen, partial} to its own 64B line; wave 0 of EVERY WG
  // polls all 256 lines (4 per lane), exits via wave-uniform __all, issues
  // one agent-acquire fence, and reduces the 256 embedded partials
  // in-register -- every WG computes the global sum itself. No aggregator,
  // no second broadcast hop. Kill switch bounds worst-case hang to ~0.4 s.
  auto arrive_wait = [&](float partial) -> float {
    ++gen;
    __syncthreads();
    if (tid == 0 && !s_dead) {
      ull word = ((ull)gen << 32) | (ull)__float_as_uint(partial);
      __hip_atomic_store(&flags[(size_t)w * 8], word, __ATOMIC_RELEASE,
                         __HIP_MEMORY_SCOPE_AGENT);
    }
    if (tid < 64 && !s_dead) {
      ull* f0 = &flags[(size_t)(tid * 4 + 0) * 8];
      ull* f1 = &flags[(size_t)(tid * 4 + 1) * 8];
      ull* f2 = &flags[(size_t)(tid * 4 + 2) * 8];
      ull* f3 = &flags[(size_t)(tid * 4 + 3) * 8];
      ull v0, v1, v2, v3;
      int spin = 0;
      for (;;) {
        v0 = __hip_atomic_load(f0, __ATOMIC_RELAXED, __HIP_MEMORY_SCOPE_AGENT);
        v1 = __hip_atomic_load(f1, __ATOMIC_RELAXED, __HIP_MEMORY_SCOPE_AGENT);
        v2 = __hip_atomic_load(f2, __ATOMIC_RELAXED, __HIP_MEMORY_SCOPE_AGENT);
        v3 = __hip_atomic_load(f3, __ATOMIC_RELAXED, __HIP_MEMORY_SCOPE_AGENT);
        bool ok = ((unsigned)(v0 >> 32) >= gen) && ((unsigned)(v1 >> 32) >= gen) &&
                  ((unsigned)(v2 >> 32) >= gen) && ((unsigned)(v3 >> 32) >= gen);
        if (__all(ok)) break;
        __builtin_amdgcn_s_sleep(1);
        if ((++spin & 127) == 0) {
          if (__hip_atomic_load(kill, __ATOMIC_RELAXED, __HIP_MEMORY_SCOPE_AGENT) != 0u ||
              spin > 400000) {
            if (tid == 0) {
              s_dead = 1;
              __hip_atomic_store(kill, 1u, __ATOMIC_RELAXED, __HIP_MEMORY_SCOPE_AGENT);
            }
            break;
          }
        }
      }
      __builtin_amdgcn_fence(__ATOMIC_ACQUIRE, "agent");
      float s = __uint_as_float((unsigned)(v0 & 0xffffffffu))
              + __uint_as_float((unsigned)(v1 & 0xffffffffu))
              + __uint_as_float((unsigned)(v2 & 0xffffffffu))
              + __uint_as_float((unsigned)(v3 & 0xffffffffu));
      s = wred64(s);
      if (tid == 0) s_b[0] = s;
    }
    __syncthreads();
    return s_b[0];
  };

  // ---------------- prologue: scalars, A row-slice + col-slice, col norms -------
  if (tid == 0) {
    s_scal[0] = sigp[0]; s_scal[1] = rhop[0]; s_scal[2] = alp[0];
    s_scal[3] = gcp[0];  s_scal[4] = gbp[0];
    s_dead = 0;
  }
  {
#pragma unroll
    for (int r = 0; r < ROWS; ++r) {
      const float* ap = A + (size_t)(row0 + r) * NDIM + j0;
      const float4 a0 = *(const float4*)(ap);
      const float4 a1 = *(const float4*)(ap + 4);
      areg[r][0] = a0.x; areg[r][1] = a0.y; areg[r][2] = a0.z; areg[r][3] = a0.w;
      areg[r][4] = a1.x; areg[r][5] = a1.y; areg[r][6] = a1.z; areg[r][7] = a1.w;
    }
    float cn = 0.f;
#pragma unroll
    for (int r = 0; r < RPT; ++r) {
      acol[r] = A[(size_t)(g * RPT + r) * NDIM + w * CPW + l];
      cn += acol[r] * acol[r];
    }
    sredA[g][l] = cn;
  }
  __syncthreads();
  if (tid < ROWS) {
    const float gb = s_scal[4];
    zb[tid] = 0.f; yb[tid] = 0.f;
    const float ee = evec[row0 + tid];
    lbs[tid] = gb * ee * lbv[row0 + tid];
    ubs[tid] = gb * ee * ubv[row0 + tid];
  }
  const float sig = s_scal[0], rho = s_scal[1], al = s_scal[2];
  float rz_cur, rz_old = 1.f;
  {
    float apart = 0.f;
    if (tid < 16) {
      xa[tid] = 0.f; xtl[tid] = 0.f;
      cs[tid] = s_scal[3] * dvec[w * 16 + tid] * cvec[w * 16 + tid];
      float S = 0.f;
#pragma unroll
      for (int q = 0; q < 32; ++q) S += sredA[q][tid];
      Md[tid] = sig + rho * S;
      const float r0 = -cs[tid];
      r_l[tid] = r0;
      const float z0 = r0 / Md[tid];
      z_g[w * 16 + tid] = z0;
      float rzv = wred16(r0 * z0);
      if (tid == 0) apart = rzv;
    }
    rz_cur = arrive_wait(apart);   // gen 1: rz0 broadcast + z_g visible
  }

  // ---------------- main loop ----------------------------------------------------
  for (int admm = 0; admm < N_ADMM; ++admm) {
    for (int cg = 0; cg < N_CG; ++cg) {
      // ---- phase 1: beta, p update, t = A p (own rows) -> t_g, pKp partial -----
      float pkp_sum;
      {
        const float beta = (cg == 0) ? 0.f : (rz_cur / rz_old);
        rz_old = rz_cur;
        const float* zp = z_g + j0;
        const float4 zv0 = *(const float4*)(zp);
        const float4 zv1 = *(const float4*)(zp + 4);
        float zl[JPT] = {zv0.x, zv0.y, zv0.z, zv0.w, zv1.x, zv1.y, zv1.z, zv1.w};
        if (cg == 0) {
#pragma unroll
          for (int k = 0; k < JPT; ++k) preg[k] = zl[k];
        } else {
#pragma unroll
          for (int k = 0; k < JPT; ++k) preg[k] = zl[k] + beta * preg[k];
        }
        if ((tid >> 1) == w) {               // stash own 16-col chunk of p
          const int b = (tid & 1) * JPT;
#pragma unroll
          for (int k = 0; k < JPT; ++k) pchunk[b + k] = preg[k];
        }
        float dp[ROWS];
#pragma unroll
        for (int r = 0; r < ROWS; ++r) {
          float s = 0.f;
#pragma unroll
          for (int k = 0; k < JPT; ++k) s += areg[r][k] * preg[k];
          dp[r] = s;
        }
#pragma unroll
        for (int r = 0; r < ROWS; ++r) {
          const float t = wred64(dp[r]);
          if ((tid & 63) == 0) dred[tid >> 6][r] = t;
        }
        __syncthreads();
        if (tid < ROWS) {
          float s = 0.f;
#pragma unroll
          for (int q = 0; q < 8; ++q) s += dred[q][tid];
          tvec[tid] = s;
          t_g[row0 + tid] = s;               // publish own t rows (8 floats)
        }
        __syncthreads();
        float apart = 0.f;
        if (tid == 0) {                      // pKp partial
          float st = 0.f;
#pragma unroll
          for (int r = 0; r < ROWS; ++r) st += tvec[r] * tvec[r];
          float sp = 0.f;
#pragma unroll
          for (int li = 0; li < 16; ++li) sp += pchunk[li] * pchunk[li];
          apart = rho * st + sig * sp;
        }
        pkp_sum = arrive_wait(apart);
      }
      // ---- phase 2: u = A^T t via col slice, x/r/z updates, rz partial ----------
      {
        const float a = rz_old / pkp_sum;
        const float4* t4 = (const float4*)t_g;
        float part = 0.f;
#pragma unroll
        for (int r4 = 0; r4 < RPT / 4; ++r4) {
          const float4 tv = t4[g * (RPT / 4) + r4];
          part += tv.x * acol[r4 * 4 + 0] + tv.y * acol[r4 * 4 + 1]
                + tv.z * acol[r4 * 4 + 2] + tv.w * acol[r4 * 4 + 3];
        }
        sredA[g][l] = part;
        __syncthreads();
        float apart = 0.f;
        if (tid < 16) {
          float S = 0.f;
#pragma unroll
          for (int q = 0; q < 32; ++q) S += sredA[q][tid];
          const float Kp = rho * S + sig * pchunk[tid];
          const float rn = r_l[tid] - a * Kp;
          r_l[tid] = rn;
          xtl[tid] += a * pchunk[tid];
          if (cg == N_CG - 1) xt_g[w * 16 + tid] = xtl[tid];
          const float zz = rn / Md[tid];
          z_g[w * 16 + tid] = zz;
          float rzv = wred16(rn * zz);
          if (tid == 0) apart = rzv;
        }
        rz_cur = arrive_wait(apart);
      }
    }
    if (admm < N_ADMM - 1) {
      // ---- phase A': ztilde = A xt (rows); z,y updates; publish t_g,u_g --------
      {
        const float* xp = xt_g + j0;
        const float4 xv0 = *(const float4*)(xp);
        const float4 xv1 = *(const float4*)(xp + 4);
        float xl[JPT] = {xv0.x, xv0.y, xv0.z, xv0.w, xv1.x, xv1.y, xv1.z, xv1.w};
        float dp[ROWS];
#pragma unroll
        for (int r = 0; r < ROWS; ++r) {
          float s = 0.f;
#pragma unroll
          for (int k = 0; k < JPT; ++k) s += areg[r][k] * xl[k];
          dp[r] = s;
        }
#pragma unroll
        for (int r = 0; r < ROWS; ++r) {
          const float t = wred64(dp[r]);
          if ((tid & 63) == 0) dred[tid >> 6][r] = t;
        }
        __syncthreads();
        if (tid < ROWS) {
          float s = 0.f;
#pragma unroll
          for (int q = 0; q < 8; ++q) s += dred[q][tid];
          t_g[row0 + tid] = s;                // raw ztilde rows (input to Kop(xt))
          const float zt = al * s + (1.f - al) * zb[tid];
          float zn = zt + yb[tid] / rho;
          zn = fminf(fmaxf(zn, lbs[tid]), ubs[tid]);
          const float yn = yb[tid] + rho * (zt - zn);
          zb[tid] = zn; yb[tid] = yn;
          u_g[row0 + tid] = rho * zn - yn;    // rhs row vector
        }
        if ((tid >> 1) == w) {                // x = al*xt + (1-al)*x on own chunk
          const int b = (tid & 1) * JPT;
#pragma unroll
          for (int k = 0; k < JPT; ++k) xa[b + k] = al * xl[k] + (1.f - al) * xa[b + k];
        }
        (void)arrive_wait(0.f);
      }
      // ---- phase B: right = sig*x - c + A^T u ; r0 = right - Kop(xt); rz0 ------
      {
        const float4* t4 = (const float4*)t_g;
        const float4* u4 = (const float4*)u_g;
        float pk = 0.f, pr = 0.f;
#pragma unroll
        for (int r4 = 0; r4 < RPT / 4; ++r4) {
          const float4 tv = t4[g * (RPT / 4) + r4];
          const float4 uv = u4[g * (RPT / 4) + r4];
          pk += tv.x * acol[r4 * 4 + 0] + tv.y * acol[r4 * 4 + 1]
              + tv.z * acol[r4 * 4 + 2] + tv.w * acol[r4 * 4 + 3];
          pr += uv.x * acol[r4 * 4 + 0] + uv.y * acol[r4 * 4 + 1]
              + uv.z * acol[r4 * 4 + 2] + uv.w * acol[r4 * 4 + 3];
        }
        sredA[g][l] = pk; sredB[g][l] = pr;
        __syncthreads();
        float apart = 0.f;
        if (tid < 16) {
          float SK = 0.f, SR = 0.f;
#pragma unroll
          for (int q = 0; q < 32; ++q) { SK += sredA[q][tid]; SR += sredB[q][tid]; }
          const float right = sig * xa[tid] - cs[tid] + SR;
          const float Kx = rho * SK + sig * xtl[tid];
          const float r0 = right - Kx;
          r_l[tid] = r0;
          const float z0 = r0 / Md[tid];
          z_g[w * 16 + tid] = z0;
          float rzv = wred16(r0 * z0);
          if (tid == 0) apart = rzv;
        }
        rz_cur = arrive_wait(apart);
      }
    }
  }
  // ---------------- final: x = al*xt + (1-al)*x ; out = x * d / gb ---------------
  if (tid < 16) {
    const float gb = s_scal[4];
    const float xf = al * xtl[tid] + (1.f - al) * xa[tid];
    out[w * 16 + tid] = xf * dvec[w * 16 + tid] / gb;
  }
}

extern "C" void kernel_launch(void* const* d_in, const int* in_sizes, int n_in,
                              void* d_out, int out_size, void* d_ws, size_t ws_size,
                              hipStream_t stream) {
  const float* A   = (const float*)d_in[0];
  const float* c   = (const float*)d_in[1];
  const float* lb  = (const float*)d_in[2];
  const float* ub  = (const float*)d_in[3];
  const float* dv  = (const float*)d_in[4];
  const float* ev  = (const float*)d_in[5];
  const float* gc  = (const float*)d_in[6];
  const float* gb  = (const float*)d_in[7];
  const float* rho = (const float*)d_in[8];
  const float* sg  = (const float*)d_in[9];
  const float* al  = (const float*)d_in[10];
  float* out = (float*)d_out;
  unsigned char* ws = (unsigned char*)d_ws;

  // zero kill/flags (first 32 KB of workspace) every call
  (void)hipMemsetAsync(d_ws, 0, 1u << 15, stream);

  admm_lp_kernel<<<dim3(NWG), dim3(NT), 0, stream>>>(
      A, c, lb, ub, dv, ev, gc, gb, rho, sg, al, out, ws);
}

// Round 8
// 5194.582 us; speedup vs baseline: 16.2775x; 1.4215x over previous
//
#include <hip/hip_runtime.h>

#define NWG 256
#define NT  512
#define ROWS 8        // rows per WG (row slice)
#define JPT 8         // cols per thread (row slice)
#define CPW 16        // cols per WG (col slice)
#define RPT 64        // rows per thread (col slice)
#define NDIM 4096
#define MROWS 2048
#define N_ADMM 30
#define N_CG 15

typedef unsigned long long ull;
typedef float f32x4 __attribute__((ext_vector_type(4)));

static_assert(NWG * ROWS == MROWS, "row partition");
static_assert(NT * JPT == NDIM, "col partition");
static_assert(NWG * CPW == NDIM, "col-slice partition");
static_assert(32 * RPT == MROWS, "col-slice rows");

__device__ __forceinline__ float wred64(float v) {
#pragma unroll
  for (int m = 32; m > 0; m >>= 1) v += __shfl_xor(v, m, 64);
  return v;
}
__device__ __forceinline__ float wred16(float v) {
  v += __shfl_xor(v, 1, 64); v += __shfl_xor(v, 2, 64);
  v += __shfl_xor(v, 4, 64); v += __shfl_xor(v, 8, 64);
  return v;
}
// Exchange-data writers: relaxed agent-scope atomics -> sc0/sc1 path to LLC,
// no L2 allocation. Readers: nontemporal loads -> no-allocate, always LLC.
// No line of the exchange buffers ever lands in an L1/L2, so no fence needed.
__device__ __forceinline__ void st64(ull* p, ull v) {
  __hip_atomic_store(p, v, __ATOMIC_RELAXED, __HIP_MEMORY_SCOPE_AGENT);
}
__device__ __forceinline__ ull ld64(const ull* p) {
  return __hip_atomic_load(p, __ATOMIC_RELAXED, __HIP_MEMORY_SCOPE_AGENT);
}
__device__ __forceinline__ f32x4 ntf4(const float* p) {
  return __builtin_nontemporal_load((const f32x4*)p);
}
__device__ __forceinline__ ull pk2(float a, float b) {
  return ((ull)__float_as_uint(b) << 32) | (ull)__float_as_uint(a);
}

__global__ __launch_bounds__(NT, 2)
void admm_lp_kernel(const float* __restrict__ A, const float* __restrict__ cvec,
                    const float* __restrict__ lbv, const float* __restrict__ ubv,
                    const float* __restrict__ dvec, const float* __restrict__ evec,
                    const float* __restrict__ gcp, const float* __restrict__ gbp,
                    const float* __restrict__ rhop, const float* __restrict__ sigp,
                    const float* __restrict__ alp,
                    float* __restrict__ out, unsigned char* __restrict__ ws)
{
  const int tid = threadIdx.x;
  const int w = blockIdx.x;
  const int j0 = tid * JPT;        // this thread's column base (row-slice work)
  const int row0 = w * ROWS;       // this WG's first row
  const int g = tid >> 4;          // col-slice row group 0..31
  const int l = tid & 15;          // col-slice column 0..15 (global col w*16+l)

  unsigned* kill  = (unsigned*)(ws + 128);      // global abort flag
  ull* flags      = (ull*)(ws + 4096);          // 256 slots, 64B stride: {gen,partial}
  float* z_g  = (float*)(ws + 32768);           // 4096 f32
  float* xt_g = (float*)(ws + 32768 + 16384);   // 4096 f32
  float* t_g  = (float*)(ws + 65536);           // 2048 f32
  float* u_g  = (float*)(ws + 65536 + 8192);    // 2048 f32
  ull* z64  = (ull*)z_g;
  ull* xt64 = (ull*)xt_g;
  ull* t64  = (ull*)t_g;
  ull* u64  = (ull*)u_g;

  __shared__ float s_scal[6];
  __shared__ float s_b[1];
  __shared__ float dred[8][ROWS];
  __shared__ float zb[ROWS], yb[ROWS], lbs[ROWS], ubs[ROWS];
  __shared__ float xa[16], cs[16], Md[16], r_l[16], pchunk[16], xtl[16];
  __shared__ float sredA[32][16], sredB[32][16];
  __shared__ int s_dead;

  float areg[ROWS][JPT];   // 64 VGPR: row slice of A
  float acol[RPT];         // 64 VGPR: col slice of A (rows g*64.., col w*16+l)
  float preg[JPT];         // col slice of CG's p

  unsigned gen = 0;

  // Fence-free fused barrier + global scalar-sum. Producer: wave-0 data
  // stores (atomic, LLC-direct) -> s_waitcnt vmcnt(0) -> flag store
  // {gen,partial}. Every WG's wave 0 polls all 256 flag lines (4/lane),
  // exits via wave-uniform __all, reduces the embedded partials in-register.
  // No buffer_wbl2 / buffer_inv anywhere. Kill switch bounds hang ~0.3 s.
  auto arrive_wait = [&](float partial) -> float {
    ++gen;
    __syncthreads();
    if (tid < 64 && !s_dead) {
      if (tid == 0) {
        __builtin_amdgcn_sched_barrier(0);
        asm volatile("s_waitcnt vmcnt(0)" ::: "memory");
        __builtin_amdgcn_sched_barrier(0);
        st64(&flags[(size_t)w * 8], ((ull)gen << 32) | (ull)__float_as_uint(partial));
      }
      ull* f0 = &flags[(size_t)(tid * 4 + 0) * 8];
      ull* f1 = &flags[(size_t)(tid * 4 + 1) * 8];
      ull* f2 = &flags[(size_t)(tid * 4 + 2) * 8];
      ull* f3 = &flags[(size_t)(tid * 4 + 3) * 8];
      ull v0, v1, v2, v3;
      int spin = 0;
      for (;;) {
        v0 = ld64(f0); v1 = ld64(f1); v2 = ld64(f2); v3 = ld64(f3);
        bool ok = ((unsigned)(v0 >> 32) >= gen) && ((unsigned)(v1 >> 32) >= gen) &&
                  ((unsigned)(v2 >> 32) >= gen) && ((unsigned)(v3 >> 32) >= gen);
        if (__all(ok)) break;
        __builtin_amdgcn_s_sleep(1);
        if ((++spin & 127) == 0) {
          if (__hip_atomic_load(kill, __ATOMIC_RELAXED, __HIP_MEMORY_SCOPE_AGENT) != 0u ||
              spin > 400000) {
            if (tid == 0) {
              s_dead = 1;
              __hip_atomic_store(kill, 1u, __ATOMIC_RELAXED, __HIP_MEMORY_SCOPE_AGENT);
            }
            break;
          }
        }
      }
      __builtin_amdgcn_sched_barrier(0);
      float s = __uint_as_float((unsigned)(v0 & 0xffffffffu))
              + __uint_as_float((unsigned)(v1 & 0xffffffffu))
              + __uint_as_float((unsigned)(v2 & 0xffffffffu))
              + __uint_as_float((unsigned)(v3 & 0xffffffffu));
      s = wred64(s);
      if (tid == 0) s_b[0] = s;
    }
    __syncthreads();
    return s_b[0];
  };

  // ---------------- prologue: scalars, A row-slice + col-slice, col norms -------
  if (tid == 0) {
    s_scal[0] = sigp[0]; s_scal[1] = rhop[0]; s_scal[2] = alp[0];
    s_scal[3] = gcp[0];  s_scal[4] = gbp[0];
    s_dead = 0;
  }
  {
#pragma unroll
    for (int r = 0; r < ROWS; ++r) {
      const float* ap = A + (size_t)(row0 + r) * NDIM + j0;
      const float4 a0 = *(const float4*)(ap);
      const float4 a1 = *(const float4*)(ap + 4);
      areg[r][0] = a0.x; areg[r][1] = a0.y; areg[r][2] = a0.z; areg[r][3] = a0.w;
      areg[r][4] = a1.x; areg[r][5] = a1.y; areg[r][6] = a1.z; areg[r][7] = a1.w;
    }
    float cn = 0.f;
#pragma unroll
    for (int r = 0; r < RPT; ++r) {
      acol[r] = A[(size_t)(g * RPT + r) * NDIM + w * CPW + l];
      cn += acol[r] * acol[r];
    }
    sredA[g][l] = cn;
  }
  __syncthreads();
  if (tid < ROWS) {
    const float gb = s_scal[4];
    zb[tid] = 0.f; yb[tid] = 0.f;
    const float ee = evec[row0 + tid];
    lbs[tid] = gb * ee * lbv[row0 + tid];
    ubs[tid] = gb * ee * ubv[row0 + tid];
  }
  const float sig = s_scal[0], rho = s_scal[1], al = s_scal[2];
  float rz_cur, rz_old = 1.f;
  {
    float zv = 0.f, apart = 0.f;
    if (tid < 16) {
      xa[tid] = 0.f; xtl[tid] = 0.f;
      cs[tid] = s_scal[3] * dvec[w * 16 + tid] * cvec[w * 16 + tid];
      float S = 0.f;
#pragma unroll
      for (int q = 0; q < 32; ++q) S += sredA[q][tid];
      Md[tid] = sig + rho * S;
      const float r0 = -cs[tid];
      r_l[tid] = r0;
      zv = r0 / Md[tid];
      float rzv = wred16(r0 * zv);
      if (tid == 0) apart = rzv;
    }
    if (tid < 64) {
      float a0 = __shfl(zv, (tid & 7) * 2, 64);
      float b0 = __shfl(zv, (tid & 7) * 2 + 1, 64);
      if (tid < 8) st64(&z64[(size_t)w * 8 + tid], pk2(a0, b0));
    }
    rz_cur = arrive_wait(apart);   // gen 1: rz0 broadcast + z_g visible
  }

  // ---------------- main loop ----------------------------------------------------
  for (int admm = 0; admm < N_ADMM; ++admm) {
    for (int cg = 0; cg < N_CG; ++cg) {
      // ---- phase 1: beta, p update, t = A p (own rows) -> t_g, pKp partial -----
      float pkp_sum;
      {
        const float beta = (cg == 0) ? 0.f : (rz_cur / rz_old);
        rz_old = rz_cur;
        const f32x4 za = ntf4(z_g + j0);
        const f32x4 zc = ntf4(z_g + j0 + 4);
        float zl[JPT] = {za.x, za.y, za.z, za.w, zc.x, zc.y, zc.z, zc.w};
        if (cg == 0) {
#pragma unroll
          for (int k = 0; k < JPT; ++k) preg[k] = zl[k];
        } else {
#pragma unroll
          for (int k = 0; k < JPT; ++k) preg[k] = zl[k] + beta * preg[k];
        }
        if ((tid >> 1) == w) {               // stash own 16-col chunk of p
          const int b = (tid & 1) * JPT;
#pragma unroll
          for (int k = 0; k < JPT; ++k) pchunk[b + k] = preg[k];
        }
        float dp[ROWS];
#pragma unroll
        for (int r = 0; r < ROWS; ++r) {
          float s = 0.f;
#pragma unroll
          for (int k = 0; k < JPT; ++k) s += areg[r][k] * preg[k];
          dp[r] = s;
        }
#pragma unroll
        for (int r = 0; r < ROWS; ++r) {
          const float t = wred64(dp[r]);
          if ((tid & 63) == 0) dred[tid >> 6][r] = t;
        }
        __syncthreads();
        float srow = 0.f;
        if (tid < ROWS) {
          float s = 0.f;
#pragma unroll
          for (int q = 0; q < 8; ++q) s += dred[q][tid];
          srow = s;
        }
        float apart = 0.f;
        if (tid < 64) {
          float st2 = srow * srow;                 // sum over rows 0..7
          st2 += __shfl_xor(st2, 1, 64);
          st2 += __shfl_xor(st2, 2, 64);
          st2 += __shfl_xor(st2, 4, 64);
          float a0 = __shfl(srow, (tid & 3) * 2, 64);
          float b0 = __shfl(srow, (tid & 3) * 2 + 1, 64);
          if (tid < 4) st64(&t64[(size_t)w * 4 + tid], pk2(a0, b0));
          if (tid == 0) {
            float sp = 0.f;
#pragma unroll
            for (int li = 0; li < 16; ++li) sp += pchunk[li] * pchunk[li];
            apart = rho * st2 + sig * sp;
          }
        }
        pkp_sum = arrive_wait(apart);
      }
      // ---- phase 2: u = A^T t via col slice, x/r/z updates, rz partial ----------
      {
        const float a = rz_old / pkp_sum;
        float part = 0.f;
#pragma unroll
        for (int r4 = 0; r4 < RPT / 4; ++r4) {
          const f32x4 tv = ntf4(t_g + g * RPT + r4 * 4);
          part += tv.x * acol[r4 * 4 + 0] + tv.y * acol[r4 * 4 + 1]
                + tv.z * acol[r4 * 4 + 2] + tv.w * acol[r4 * 4 + 3];
        }
        sredA[g][l] = part;
        __syncthreads();
        float zzv = 0.f, xtv = 0.f, apart = 0.f;
        if (tid < 16) {
          float S = 0.f;
#pragma unroll
          for (int q = 0; q < 32; ++q) S += sredA[q][tid];
          const float Kp = rho * S + sig * pchunk[tid];
          const float rn = r_l[tid] - a * Kp;
          r_l[tid] = rn;
          xtl[tid] += a * pchunk[tid];
          xtv = xtl[tid];
          zzv = rn / Md[tid];
          float rzv = wred16(rn * zzv);
          if (tid == 0) apart = rzv;
        }
        if (tid < 64) {
          float a0 = __shfl(zzv, (tid & 7) * 2, 64);
          float b0 = __shfl(zzv, (tid & 7) * 2 + 1, 64);
          if (tid < 8) st64(&z64[(size_t)w * 8 + tid], pk2(a0, b0));
          if (cg == N_CG - 1) {
            float c0 = __shfl(xtv, (tid & 7) * 2, 64);
            float d0 = __shfl(xtv, (tid & 7) * 2 + 1, 64);
            if (tid < 8) st64(&xt64[(size_t)w * 8 + tid], pk2(c0, d0));
          }
        }
        rz_cur = arrive_wait(apart);
      }
    }
    if (admm < N_ADMM - 1) {
      // ---- phase A': ztilde = A xt (rows); z,y updates; publish t_g,u_g --------
      {
        const f32x4 xv0 = ntf4(xt_g + j0);
        const f32x4 xv1 = ntf4(xt_g + j0 + 4);
        float xl[JPT] = {xv0.x, xv0.y, xv0.z, xv0.w, xv1.x, xv1.y, xv1.z, xv1.w};
        float dp[ROWS];
#pragma unroll
        for (int r = 0; r < ROWS; ++r) {
          float s = 0.f;
#pragma unroll
          for (int k = 0; k < JPT; ++k) s += areg[r][k] * xl[k];
          dp[r] = s;
        }
#pragma unroll
        for (int r = 0; r < ROWS; ++r) {
          const float t = wred64(dp[r]);
          if ((tid & 63) == 0) dred[tid >> 6][r] = t;
        }
        __syncthreads();
        float srow = 0.f, urow = 0.f;
        if (tid < ROWS) {
          float s = 0.f;
#pragma unroll
          for (int q = 0; q < 8; ++q) s += dred[q][tid];
          srow = s;                           // raw ztilde rows (input to Kop(xt))
          const float zt = al * s + (1.f - al) * zb[tid];
          float zn = zt + yb[tid] / rho;
          zn = fminf(fmaxf(zn, lbs[tid]), ubs[tid]);
          const float yn = yb[tid] + rho * (zt - zn);
          zb[tid] = zn; yb[tid] = yn;
          urow = rho * zn - yn;               // rhs row vector
        }
        if (tid < 64) {
          float ta = __shfl(srow, (tid & 3) * 2, 64);
          float tb = __shfl(srow, (tid & 3) * 2 + 1, 64);
          float ua = __shfl(urow, (tid & 3) * 2, 64);
          float ub = __shfl(urow, (tid & 3) * 2 + 1, 64);
          if (tid < 4) {
            st64(&t64[(size_t)w * 4 + tid], pk2(ta, tb));
            st64(&u64[(size_t)w * 4 + tid], pk2(ua, ub));
          }
        }
        if ((tid >> 1) == w) {                // x = al*xt + (1-al)*x on own chunk
          const int b = (tid & 1) * JPT;
#pragma unroll
          for (int k = 0; k < JPT; ++k) xa[b + k] = al * xl[k] + (1.f - al) * xa[b + k];
        }
        (void)arrive_wait(0.f);
      }
      // ---- phase B: right = sig*x - c + A^T u ; r0 = right - Kop(xt); rz0 ------
      {
        float pk = 0.f, pr = 0.f;
#pragma unroll
        for (int r4 = 0; r4 < RPT / 4; ++r4) {
          const f32x4 tv = ntf4(t_g + g * RPT + r4 * 4);
          const f32x4 uv = ntf4(u_g + g * RPT + r4 * 4);
          pk += tv.x * acol[r4 * 4 + 0] + tv.y * acol[r4 * 4 + 1]
              + tv.z * acol[r4 * 4 + 2] + tv.w * acol[r4 * 4 + 3];
          pr += uv.x * acol[r4 * 4 + 0] + uv.y * acol[r4 * 4 + 1]
              + uv.z * acol[r4 * 4 + 2] + uv.w * acol[r4 * 4 + 3];
        }
        sredA[g][l] = pk; sredB[g][l] = pr;
        __syncthreads();
        float zv = 0.f, apart = 0.f;
        if (tid < 16) {
          float SK = 0.f, SR = 0.f;
#pragma unroll
          for (int q = 0; q < 32; ++q) { SK += sredA[q][tid]; SR += sredB[q][tid]; }
          const float right = sig * xa[tid] - cs[tid] + SR;
          const float Kx = rho * SK + sig * xtl[tid];
          const float r0 = right - Kx;
          r_l[tid] = r0;
          zv = r0 / Md[tid];
          float rzv = wred16(r0 * zv);
          if (tid == 0) apart = rzv;
        }
        if (tid < 64) {
          float a0 = __shfl(zv, (tid & 7) * 2, 64);
          float b0 = __shfl(zv, (tid & 7) * 2 + 1, 64);
          if (tid < 8) st64(&z64[(size_t)w * 8 + tid], pk2(a0, b0));
        }
        rz_cur = arrive_wait(apart);
      }
    }
  }
  // ---------------- final: x = al*xt + (1-al)*x ; out = x * d / gb ---------------
  if (tid < 16) {
    const float gb = s_scal[4];
    const float xf = al * xtl[tid] + (1.f - al) * xa[tid];
    out[w * 16 + tid] = xf * dvec[w * 16 + tid] / gb;
  }
}

extern "C" void kernel_launch(void* const* d_in, const int* in_sizes, int n_in,
                              void* d_out, int out_size, void* d_ws, size_t ws_size,
                              hipStream_t stream) {
  const float* A   = (const float*)d_in[0];
  const float* c   = (const float*)d_in[1];
  const float* lb  = (const float*)d_in[2];
  const float* ub  = (const float*)d_in[3];
  const float* dv  = (const float*)d_in[4];
  const float* ev  = (const float*)d_in[5];
  const float* gc  = (const float*)d_in[6];
  const float* gb  = (const float*)d_in[7];
  const float* rho = (const float*)d_in[8];
  const float* sg  = (const float*)d_in[9];
  const float* al  = (const float*)d_in[10];
  float* out = (float*)d_out;
  unsigned char* ws = (unsigned char*)d_ws;

  // zero kill/flags (first 32 KB of workspace) every call
  (void)hipMemsetAsync(d_ws, 0, 1u << 15, stream);

  admm_lp_kernel<<<dim3(NWG), dim3(NT), 0, stream>>>(
      A, c, lb, ub, dv, ev, gc, gb, rho, sg, al, out, ws);
}